// Round 7
// baseline (598.284 us; speedup 1.0000x reference)
//
#include <hip/hip_runtime.h>
#include <hip/hip_bf16.h>

// Problem dims (fixed by setup_inputs)
#define S   2048
#define D   1024
#define DFF 4096
#define NH  16
#define HD  64

typedef unsigned short u16;
typedef unsigned int   u32;
typedef __attribute__((ext_vector_type(8))) short      short8;  // 8 bf16
typedef __attribute__((ext_vector_type(4))) float      floatx4; // MFMA C/D
typedef __attribute__((ext_vector_type(2))) _Float16   half2v;
typedef __attribute__((ext_vector_type(8))) _Float16   half8v;

__device__ __forceinline__ float bu2f(u16 u) {
    union { u32 i; float f; } x; x.i = ((u32)u) << 16; return x.f;
}
__device__ __forceinline__ u16 f2bu(float f) {
    __hip_bfloat16 h = __float2bfloat16(f);
    return *(u16*)&h;
}
__device__ __forceinline__ u16 f2h(float f) {
    _Float16 h = (_Float16)f; return *(u16*)&h;
}
__device__ __forceinline__ float ldf(const float* p) { return *p; }
__device__ __forceinline__ float ldf(const u16* p)   { return bu2f(*p); }

// cvt_pkrtz returns __fp16x2; bit-cast to our _Float16x2 (same 32-bit reg)
__device__ __forceinline__ half2v pkrtz(float a, float b) {
    auto v = __builtin_amdgcn_cvt_pkrtz(a, b);
    union { decltype(v) i; half2v o; } u; u.i = v; return u.o;
}

__device__ __forceinline__ floatx4 mfma_f16(half8v a, half8v b, floatx4 c) {
    return __builtin_amdgcn_mfma_f32_16x16x32_f16(a, b, c, 0, 0, 0);
}
__device__ __forceinline__ float fdot2f(half2v a, half2v b, float c) {
#if __has_builtin(__builtin_amdgcn_fdot2)
    return __builtin_amdgcn_fdot2(a, b, c, false);
#else
    return c + (float)a[0] * (float)b[0] + (float)a[1] * (float)b[1];
#endif
}

// async global->LDS, 16B per lane, lands at ldsbase + lane*16
__device__ __forceinline__ void async16(const void* g, void* l) {
    __builtin_amdgcn_global_load_lds(
        (const __attribute__((address_space(1))) u32*)g,
        (__attribute__((address_space(3))) u32*)l, 16, 0, 0);
}

// ---------------- fp32 -> bf16 bulk convert (weights) ------------------------
__global__ __launch_bounds__(256)
void cvt_kernel(const float* __restrict__ in, u16* __restrict__ out, int n4)
{
    int i = blockIdx.x * 256 + threadIdx.x;
    if (i < n4) {
        float4 v = ((const float4*)in)[i];
        ushort4 s;
        s.x = f2bu(v.x); s.y = f2bu(v.y); s.z = f2bu(v.z); s.w = f2bu(v.w);
        ((ushort4*)out)[i] = s;
    }
}

// ---------------- LayerNorm: one block per row, D=1024, 256 threads ----------
template <typename T>
__global__ __launch_bounds__(256, 4)
void ln_kernel(const T* __restrict__ in, const float* __restrict__ ga,
               const float* __restrict__ gb, u16* __restrict__ out)
{
    const int row = blockIdx.x;
    const int t = threadIdx.x;
    const T* x = in + (size_t)row * D;
    float v[4];
    float s = 0.f, ss = 0.f;
#pragma unroll
    for (int j = 0; j < 4; j++) {
        float val = ldf(x + t + 256 * j);
        v[j] = val; s += val; ss = fmaf(val, val, ss);
    }
#pragma unroll
    for (int off = 32; off >= 1; off >>= 1) {
        s  += __shfl_down(s,  off, 64);
        ss += __shfl_down(ss, off, 64);
    }
    __shared__ float red[10];
    const int wave = t >> 6, lane = t & 63;
    if (lane == 0) { red[wave] = s; red[4 + wave] = ss; }
    __syncthreads();
    if (t == 0) {
        float S1 = red[0] + red[1] + red[2] + red[3];
        float S2 = red[4] + red[5] + red[6] + red[7];
        float mu = S1 / (float)D;
        float var = (S2 - (float)D * mu * mu) / (float)(D - 1);  // ddof=1
        float sig = sqrtf(fmaxf(var, 0.f)) + 1e-6f;              // eps on sigma
        red[8] = mu; red[9] = 1.f / sig;
    }
    __syncthreads();
    const float mu = red[8], rs = red[9];
#pragma unroll
    for (int j = 0; j < 4; j++) {
        int c = t + 256 * j;
        out[(size_t)row * D + c] = f2bu((v[j] - mu) * rs * ga[c] + gb[c]);
    }
}

// ======================= MFMA GEMM core (128x128 tile) =======================
#define GEMM_CORE(A_, B_, K_)                                                   \
    __shared__ u16 As[128 * 32];                                                \
    __shared__ u16 Bs[128 * 32];                                                \
    const int t = threadIdx.x;                                                  \
    const int w = t >> 6, l = t & 63;                                           \
    const int m0 = blockIdx.y * 128, n0 = blockIdx.x * 128;                     \
    const int qk = l >> 4, col = l & 15;                                        \
    const int wm = (w & 1) * 64, wn = (w >> 1) * 64;                            \
    const int sr  = l >> 2;                                                     \
    const int sq  = l & 3;                                                      \
    const int row = w * 16 + sr;                                                \
    const int gq  = sq ^ ((row >> 1) & 3);                                      \
    const u16* Ap = A_ + (size_t)(m0 + row) * K_ + gq * 8;                      \
    const u16* Bp = B_ + (size_t)(n0 + row) * K_ + gq * 8;                      \
    u16* AsW = As + w * 16 * 32;                                                \
    u16* BsW = Bs + w * 16 * 32;                                                \
    const int mloc = wm + col, nloc = wn + col;                                 \
    const u16* aBase = As + mloc * 32 + (qk ^ ((mloc >> 1) & 3)) * 8;           \
    const u16* bBase = Bs + nloc * 32 + (qk ^ ((nloc >> 1) & 3)) * 8;           \
    floatx4 acc[4][4];                                                          \
    _Pragma("unroll")                                                           \
    for (int i = 0; i < 4; i++)                                                 \
        _Pragma("unroll")                                                       \
        for (int j = 0; j < 4; j++) acc[i][j] = (floatx4)0.f;                   \
    for (int k0 = 0; k0 < K_; k0 += 32) {                                       \
        __syncthreads();                                                        \
        async16(Ap,                  AsW);                                      \
        async16(Ap + (size_t)64 * K_, AsW + 64 * 32);                           \
        async16(Bp,                  BsW);                                      \
        async16(Bp + (size_t)64 * K_, BsW + 64 * 32);                           \
        Ap += 32; Bp += 32;                                                     \
        __syncthreads();                                                        \
        short8 a[4], b[4];                                                      \
        _Pragma("unroll")                                                       \
        for (int i = 0; i < 4; i++) a[i] = *(const short8*)(aBase + i * 16 * 32);\
        _Pragma("unroll")                                                       \
        for (int j = 0; j < 4; j++) b[j] = *(const short8*)(bBase + j * 16 * 32);\
        _Pragma("unroll")                                                       \
        for (int i = 0; i < 4; i++)                                             \
            _Pragma("unroll")                                                   \
            for (int j = 0; j < 4; j++)                                         \
                acc[i][j] = __builtin_amdgcn_mfma_f32_16x16x32_bf16(            \
                    a[i], b[j], acc[i][j], 0, 0, 0);                            \
    }

// ---- generic GEMM 128x128 (+bias/relu/res), OMODE 0 f32 / 1 bf16 ------------
template <int OMODE, bool RELU, int RES>
__global__ __launch_bounds__(256, 2)
void gemm_mfma(const u16* __restrict__ A, const u16* __restrict__ B,
               const float* __restrict__ bias, const void* __restrict__ res,
               void* __restrict__ Cout, int M, int N, int K)
{
    GEMM_CORE(A, B, K)
#pragma unroll
    for (int j = 0; j < 4; j++) {
        const int n = n0 + wn + j * 16 + col;
        const float bn = bias[n];
#pragma unroll
        for (int i = 0; i < 4; i++) {
#pragma unroll
            for (int r = 0; r < 4; r++) {
                const int m = m0 + wm + i * 16 + qk * 4 + r;
                float v = acc[i][j][r] + bn;
                if (RELU) v = fmaxf(v, 0.f);
                if (RES == 1) v += ((const float*)res)[(size_t)m * N + n];
                if (RES == 2) v += bu2f(((const u16*)res)[(size_t)m * N + n]);
                if (OMODE == 0) ((float*)Cout)[(size_t)m * N + n] = v;
                if (OMODE == 1) ((u16*)Cout)[(size_t)m * N + n] = f2bu(v);
            }
        }
    }
}

// ---- fused QKV GEMM (128x128): outputs f16 Q [S,D], K [S,D], V^T [D,S] ------
__global__ __launch_bounds__(256, 2)
void gemm_qkv(const u16* __restrict__ A, const u16* __restrict__ B,
              const float* __restrict__ bq, const float* __restrict__ bk,
              const float* __restrict__ bv, u16* __restrict__ outQ,
              u16* __restrict__ outK, u16* __restrict__ outVT)
{
    const int K = D;
    GEMM_CORE(A, B, K)
    const int seg   = n0 >> 10;
    const int nbase = n0 & 1023;
    const float* bs = (seg == 0) ? bq : (seg == 1) ? bk : bv;
    u16* outMN = (seg == 0) ? outQ : outK;
#pragma unroll
    for (int j = 0; j < 4; j++) {
        const int nl = nbase + wn + j * 16 + col;
        const float bn = bs[nl];
#pragma unroll
        for (int i = 0; i < 4; i++) {
#pragma unroll
            for (int r = 0; r < 4; r++) {
                const int m = m0 + wm + i * 16 + qk * 4 + r;
                float v = acc[i][j][r] + bn;
                if (seg < 2) outMN[(size_t)m * D + nl] = f2h(v);
                else         outVT[(size_t)nl * S + m] = f2h(v);
            }
        }
    }
}

// ---- 128x64-tile GEMM (2x the blocks for N=1024 outputs: WO, FFN2) ----------
template <int OMODE, int RES>
__global__ __launch_bounds__(256, 2)
void gemm_mfma64(const u16* __restrict__ A, const u16* __restrict__ B,
                 const float* __restrict__ bias, const void* __restrict__ res,
                 void* __restrict__ Cout, int M, int N, int K)
{
    __shared__ u16 As[128 * 32];
    __shared__ u16 Bs[64 * 32];
    const int t = threadIdx.x;
    const int w = t >> 6, l = t & 63;
    const int m0 = blockIdx.y * 128, n0 = blockIdx.x * 64;
    const int qk = l >> 4, col = l & 15;
    const int wm = (w & 1) * 64, wn = (w >> 1) * 32;
    const int sr = l >> 2, sq = l & 3;
    const int row = w * 16 + sr;
    const int gq = sq ^ ((row >> 1) & 3);
    const u16* Ap = A + (size_t)(m0 + row) * K + gq * 8;
    const u16* Bp = B + (size_t)(n0 + row) * K + gq * 8;
    u16* AsW = As + w * 16 * 32;
    u16* BsW = Bs + w * 16 * 32;
    const int mloc = wm + col, nloc = wn + col;
    const u16* aBase = As + mloc * 32 + (qk ^ ((mloc >> 1) & 3)) * 8;
    const u16* bBase = Bs + nloc * 32 + (qk ^ ((nloc >> 1) & 3)) * 8;
    floatx4 acc[4][2];
#pragma unroll
    for (int i = 0; i < 4; i++)
#pragma unroll
        for (int j = 0; j < 2; j++) acc[i][j] = (floatx4)0.f;
    for (int k0 = 0; k0 < K; k0 += 32) {
        __syncthreads();
        async16(Ap, AsW);
        async16(Ap + (size_t)64 * K, AsW + 64 * 32);
        async16(Bp, BsW);
        Ap += 32; Bp += 32;
        __syncthreads();
        short8 a[4], b[2];
#pragma unroll
        for (int i = 0; i < 4; i++) a[i] = *(const short8*)(aBase + i * 16 * 32);
#pragma unroll
        for (int j = 0; j < 2; j++) b[j] = *(const short8*)(bBase + j * 16 * 32);
#pragma unroll
        for (int i = 0; i < 4; i++)
#pragma unroll
            for (int j = 0; j < 2; j++)
                acc[i][j] = __builtin_amdgcn_mfma_f32_16x16x32_bf16(
                    a[i], b[j], acc[i][j], 0, 0, 0);
    }
#pragma unroll
    for (int j = 0; j < 2; j++) {
        const int n = n0 + wn + j * 16 + col;
        const float bn = bias[n];
#pragma unroll
        for (int i = 0; i < 4; i++) {
#pragma unroll
            for (int r = 0; r < 4; r++) {
                const int m = m0 + wm + i * 16 + qk * 4 + r;
                float v = acc[i][j][r] + bn;
                if (RES == 1) v += ((const float*)res)[(size_t)m * N + n];
                if (RES == 2) v += bu2f(((const u16*)res)[(size_t)m * N + n]);
                if (OMODE == 0) ((float*)Cout)[(size_t)m * N + n] = v;
                if (OMODE == 1) ((u16*)Cout)[(size_t)m * N + n] = f2bu(v);
            }
        }
    }
}

// =================== f16 MFMA fused sparse attention =========================
// Block: 16 q-rows of one head, 4 waves, grid NH*128 = 2048.
// Wave w owns tiles T = 4i+w (key-interleaved) -> every 512-key chunk is
// self-contained. Scores packed f16 pairs in VGPRs; Newton via pk-f16 + fdot2;
// P streamed through an 18 KB swizzled LDS chunk; PV accumulates across chunks.
__global__ __launch_bounds__(256, 3)
void attn_f16(const u16* __restrict__ qb, const u16* __restrict__ kb,
              const u16* __restrict__ vT, const int* __restrict__ mask,
              u16* __restrict__ att)
{
    __shared__ u16  Plds[16 * 544];     // [row][512+32 pad] f16, 8-key-block swizzle
    __shared__ float red[256];          // cross-wave reduce, double-buffered
    const int h  = blockIdx.x >> 7;
    const int q0 = (blockIdx.x & 127) * 16;
    const int t  = threadIdx.x;
    const int w  = t >> 6, l = t & 63;
    const int lg = l >> 4, lc = l & 15;

    // Q a-frags (f16): A[m=lc][k=lg*8+j], two K=32 halves of HD=64
    const u16* qp = qb + (size_t)(q0 + lc) * D + h * HD + lg * 8;
    const half8v aq0 = *(const half8v*)qp;
    const half8v aq1 = *(const half8v*)(qp + 32);

    half2v sf[4][16];   // rows lg*4+r, pair p holds tiles (2p, 2p+1) of this wave
    {
        const u16* kbase = kb + h * HD + lg * 8;
#pragma unroll 4
        for (int p = 0; p < 16; p++) {
            const int T0 = 8 * p + w;       // tile 4*(2p)+w
            const int T1 = T0 + 4;          // tile 4*(2p+1)+w
            const u16* kp0 = kbase + (size_t)(T0 * 16 + lc) * D;
            const u16* kp1 = kbase + (size_t)(T1 * 16 + lc) * D;
            floatx4 a0 = (floatx4)0.f, a1 = (floatx4)0.f;
            a0 = mfma_f16(aq0, *(const half8v*)kp0,        a0);
            a0 = mfma_f16(aq1, *(const half8v*)(kp0 + 32), a0);
            a1 = mfma_f16(aq0, *(const half8v*)kp1,        a1);
            a1 = mfma_f16(aq1, *(const half8v*)(kp1 + 32), a1);
            const int mk0 = mask[T0 * 16 + lc];
            const int mk1 = mask[T1 * 16 + lc];
            // scale = (1/sqrt(64))*(1/2 from entmax) = 0.0625; masked -> -3e4 (f16-safe)
#pragma unroll
            for (int r = 0; r < 4; r++) {
                float s0 = mk0 ? a0[r] * 0.0625f : -30000.f;
                float s1 = mk1 ? a1[r] * 0.0625f : -30000.f;
                sf[r][p] = pkrtz(s0, s1);
            }
        }
    }

    const half2v hz = {(_Float16)0.f, (_Float16)0.f};
    const half2v h1 = {(_Float16)1.f, (_Float16)1.f};
    float tau[4];

    // ---- row max -> tau0 = mx - 1 (monotone Newton start, g(tau0) >= 1) ----
    {
#pragma unroll
        for (int r = 0; r < 4; r++) {
            half2v mm = sf[r][0];
#pragma unroll
            for (int p = 1; p < 16; p++) mm = __builtin_elementwise_max(mm, sf[r][p]);
            float mx = fmaxf((float)mm[0], (float)mm[1]);
#pragma unroll
            for (int off = 1; off <= 8; off <<= 1)
                mx = fmaxf(mx, __shfl_xor(mx, off, 64));
            if (lc == 0) red[w * 32 + (lg * 4 + r) * 2] = mx;
        }
        __syncthreads();
#pragma unroll
        for (int r = 0; r < 4; r++) {
            const int rowi = (lg * 4 + r) * 2;
            float m = fmaxf(fmaxf(red[rowi], red[32 + rowi]),
                            fmaxf(red[64 + rowi], red[96 + rowi]));
            tau[r] = m - 1.0f;
        }
    }

    // ---- Newton on g(tau) = sum relu(x-tau)^2 = 1 : 10 iters, fdot2 kernel ----
    for (int it = 0; it < 10; it++) {
        const int pb = ((it + 1) & 1) * 128;
#pragma unroll
        for (int r = 0; r < 4; r++) {
            half2v t2 = pkrtz(tau[r], tau[r]);
            float s1 = 0.f, s2 = 0.f;
#pragma unroll
            for (int p = 0; p < 16; p++) {
                half2v dp = __builtin_elementwise_max(sf[r][p] - t2, hz);
                s1 = fdot2f(dp, h1, s1);
                s2 = fdot2f(dp, dp, s2);
            }
#pragma unroll
            for (int off = 1; off <= 8; off <<= 1) {
                s1 += __shfl_xor(s1, off, 64);
                s2 += __shfl_xor(s2, off, 64);
            }
            if (lc == 0) {
                red[pb + w * 32 + (lg * 4 + r) * 2]     = s1;
                red[pb + w * 32 + (lg * 4 + r) * 2 + 1] = s2;
            }
        }
        __syncthreads();
#pragma unroll
        for (int r = 0; r < 4; r++) {
            const int rowi = (lg * 4 + r) * 2;
            float S1 = red[pb + rowi] + red[pb + 32 + rowi]
                     + red[pb + 64 + rowi] + red[pb + 96 + rowi];
            float S2 = red[pb + 1 + rowi] + red[pb + 33 + rowi]
                     + red[pb + 65 + rowi] + red[pb + 97 + rowi];
            tau[r] += (S2 - 1.0f) / (2.0f * S1);   // S1 >= S2 >= 1-eps : safe
        }
    }

    half2v t2f[4];
#pragma unroll
    for (int r = 0; r < 4; r++) t2f[r] = pkrtz(tau[r], tau[r]);

    // ---- 4 chunks of 512 keys: P -> LDS (swizzled) -> PV MFMA accumulate ----
    floatx4 oacc = (floatx4)0.f;
    const u16* vp = vT + (size_t)(h * HD + w * 16 + lc) * S + lg * 8;
    for (int c = 0; c < 4; c++) {
        if (c) __syncthreads();             // prior chunk's PV reads done
#pragma unroll
        for (int m = 0; m < 4; m++) {
            const int kl0 = 128 * m + 16 * w + lc;   // and kl0+64
            const int b0 = kl0 >> 3, b1 = b0 + 8;
            const int k7 = kl0 & 7;
#pragma unroll
            for (int r = 0; r < 4; r++) {
                half2v dp = __builtin_elementwise_max(sf[r][4 * c + m] - t2f[r], hz);
                half2v pp = dp * dp;
                u32 bits;
                __builtin_memcpy(&bits, &pp, 4);
                const int row = lg * 4 + r;
                const int x = (row >> 1) & 3;
                const int p0 = (b0 & ~3) | ((b0 & 3) ^ x);
                const int p1 = (b1 & ~3) | ((b1 & 3) ^ x);
                Plds[row * 544 + p0 * 8 + k7] = (u16)bits;
                Plds[row * 544 + p1 * 8 + k7] = (u16)(bits >> 16);
            }
        }
        __syncthreads();
        const u16* vpc = vp + 512 * c;
#pragma unroll
        for (int s = 0; s < 16; s++) {
            const int bb = 4 * s + lg;
            const int pbk = (bb & ~3) | ((bb & 3) ^ ((lc >> 1) & 3));
            half8v af = *(const half8v*)&Plds[lc * 544 + pbk * 8];
            half8v bf = *(const half8v*)(vpc + 32 * s);
            oacc = mfma_f16(af, bf, oacc);
        }
    }
#pragma unroll
    for (int r = 0; r < 4; r++)
        att[(size_t)(q0 + lg * 4 + r) * D + h * HD + w * 16 + lc] = f2bu(oacc[r]);
}

// ---------------- host side ---------------------------------------------------
extern "C" void kernel_launch(void* const* d_in, const int* in_sizes, int n_in,
                              void* d_out, int out_size, void* d_ws, size_t ws_size,
                              hipStream_t stream)
{
    const float* inp  = (const float*)d_in[0];
    const int*   mask = (const int*)d_in[1];
    const float* wq   = (const float*)d_in[2];
    const float* bq   = (const float*)d_in[3];
    const float* wk   = (const float*)d_in[4];
    const float* bk   = (const float*)d_in[5];
    const float* wv   = (const float*)d_in[6];
    const float* bv   = (const float*)d_in[7];
    const float* wo   = (const float*)d_in[8];
    const float* bo   = (const float*)d_in[9];
    const float* ln1a = (const float*)d_in[10];
    const float* ln1b = (const float*)d_in[11];
    const float* w1   = (const float*)d_in[12];
    const float* b1   = (const float*)d_in[13];
    const float* w2   = (const float*)d_in[14];
    const float* b2   = (const float*)d_in[15];
    const float* ln2a = (const float*)d_in[16];
    const float* ln2b = (const float*)d_in[17];

    const size_t MB = 1u << 20;
    char* w = (char*)d_ws;
    // 32 MB overlay (16-bit bufs unless noted):
    //  [0,8):  wqkvb(6MB) -> w1b (after QKV) -> w2b (after FFN1)
    //  [8,12): x1 -> att -> x2   (bf16)
    //  [12,16): qb_ (f16) -> yb (bf16)
    //  [16,20): kb_ (f16)  \
    //  [20,24): vTb (f16)   > dead after attn -> hb [16,32)
    //  [24,26): wob (bf16) /  (dead after WO, before FFN1 writes hb)
    u16* wqkvb = (u16*)(w + 0 * MB);
    u16* w1b   = (u16*)(w + 0 * MB);
    u16* w2b   = (u16*)(w + 0 * MB);
    u16* x1    = (u16*)(w + 8 * MB);
    u16* att   = x1;
    u16* x2    = x1;
    u16* qb_   = (u16*)(w + 12 * MB);
    u16* yb    = (u16*)(w + 12 * MB);
    u16* kb_   = (u16*)(w + 16 * MB);
    u16* vTb   = (u16*)(w + 20 * MB);
    u16* wob   = (u16*)(w + 24 * MB);
    u16* hb    = (u16*)(w + 16 * MB);
    float* outF = (float*)d_out;

    // 0. weight conversions: QKV concat + WO
    cvt_kernel<<<1024, 256, 0, stream>>>(wq, wqkvb,                   (D * D) / 4);
    cvt_kernel<<<1024, 256, 0, stream>>>(wk, wqkvb + 1024 * 1024,     (D * D) / 4);
    cvt_kernel<<<1024, 256, 0, stream>>>(wv, wqkvb + 2 * 1024 * 1024, (D * D) / 4);
    cvt_kernel<<<1024, 256, 0, stream>>>(wo, wob, (D * D) / 4);
    // 1. LN1 -> bf16
    ln_kernel<float><<<S, 256, 0, stream>>>(inp, ln1a, ln1b, x1);
    // 2. fused QKV projection -> f16 Q [S,D], K [S,D], V^T [D,S]
    gemm_qkv<<<dim3(3 * D / 128, S / 128), 256, 0, stream>>>(
        x1, wqkvb, bq, bk, bv, qb_, kb_, vTb);
    // 3. convert w1 (wqkvb dead)
    cvt_kernel<<<4096, 256, 0, stream>>>(w1, w1b, (DFF * D) / 4);
    // 4. f16 MFMA fused entmax attention -> att bf16 (over x1 slot)
    attn_f16<<<NH * (S / 16), 256, 0, stream>>>(qb_, kb_, vTb, mask, att);
    // 5. WO projection + residual(inp fp32) -> yb bf16  (256 blocks)
    gemm_mfma64<1, 1><<<dim3(D / 64, S / 128), 256, 0, stream>>>(
        att, wob, bo, inp, yb, S, D, D);
    // 6. LN2 -> x2 (att dead)
    ln_kernel<u16><<<S, 256, 0, stream>>>(yb, ln2a, ln2b, x2);
    // 7. FFN1 (+ReLU) -> hb bf16 (kb_/vTb/wob dead)
    gemm_mfma<1, true, 0><<<dim3(DFF / 128, S / 128), 256, 0, stream>>>(
        x2, w1b, b1, nullptr, hb, S, DFF, D);
    // 8. convert w2 (w1b dead)
    cvt_kernel<<<4096, 256, 0, stream>>>(w2, w2b, (DFF * D) / 4);
    // 9. FFN2 + residual(yb bf16) -> fp32 out  (256 blocks)
    gemm_mfma64<0, 2><<<dim3(D / 64, S / 128), 256, 0, stream>>>(
        hb, w2b, b2, yb, outF, S, D, DFF);
}

// Round 8
// 597.349 us; speedup vs baseline: 1.0016x; 1.0016x over previous
//
#include <hip/hip_runtime.h>
#include <hip/hip_bf16.h>

// Problem dims (fixed by setup_inputs)
#define S   2048
#define D   1024
#define DFF 4096
#define NH  16
#define HD  64

typedef unsigned short u16;
typedef unsigned int   u32;
typedef __attribute__((ext_vector_type(8))) short      short8;  // 8 bf16
typedef __attribute__((ext_vector_type(4))) float      floatx4; // MFMA C/D
typedef __attribute__((ext_vector_type(2))) _Float16   half2v;
typedef __attribute__((ext_vector_type(8))) _Float16   half8v;

__device__ __forceinline__ float bu2f(u16 u) {
    union { u32 i; float f; } x; x.i = ((u32)u) << 16; return x.f;
}
__device__ __forceinline__ u16 f2bu(float f) {
    __hip_bfloat16 h = __float2bfloat16(f);
    return *(u16*)&h;
}
__device__ __forceinline__ u16 f2h(float f) {
    _Float16 h = (_Float16)f; return *(u16*)&h;
}
__device__ __forceinline__ float ldf(const float* p) { return *p; }
__device__ __forceinline__ float ldf(const u16* p)   { return bu2f(*p); }

// cvt_pkrtz returns __fp16x2; bit-cast to our _Float16x2 (same 32-bit reg)
__device__ __forceinline__ half2v pkrtz(float a, float b) {
    auto v = __builtin_amdgcn_cvt_pkrtz(a, b);
    union { decltype(v) i; half2v o; } u; u.i = v; return u.o;
}

__device__ __forceinline__ floatx4 mfma_f16(half8v a, half8v b, floatx4 c) {
    return __builtin_amdgcn_mfma_f32_16x16x32_f16(a, b, c, 0, 0, 0);
}
__device__ __forceinline__ float fdot2f(half2v a, half2v b, float c) {
#if __has_builtin(__builtin_amdgcn_fdot2)
    return __builtin_amdgcn_fdot2(a, b, c, false);
#else
    return c + (float)a[0] * (float)b[0] + (float)a[1] * (float)b[1];
#endif
}

// async global->LDS, 16B per lane, lands at ldsbase + lane*16
__device__ __forceinline__ void async16(const void* g, void* l) {
    __builtin_amdgcn_global_load_lds(
        (const __attribute__((address_space(1))) u32*)g,
        (__attribute__((address_space(3))) u32*)l, 16, 0, 0);
}

// ---------------- fp32 -> bf16 bulk convert (weights) ------------------------
__global__ __launch_bounds__(256)
void cvt_kernel(const float* __restrict__ in, u16* __restrict__ out, int n4)
{
    int i = blockIdx.x * 256 + threadIdx.x;
    if (i < n4) {
        float4 v = ((const float4*)in)[i];
        ushort4 s;
        s.x = f2bu(v.x); s.y = f2bu(v.y); s.z = f2bu(v.z); s.w = f2bu(v.w);
        ((ushort4*)out)[i] = s;
    }
}

// ---------------- LayerNorm: one block per row, D=1024, 256 threads ----------
template <typename T>
__global__ __launch_bounds__(256, 4)
void ln_kernel(const T* __restrict__ in, const float* __restrict__ ga,
               const float* __restrict__ gb, u16* __restrict__ out)
{
    const int row = blockIdx.x;
    const int t = threadIdx.x;
    const T* x = in + (size_t)row * D;
    float v[4];
    float s = 0.f, ss = 0.f;
#pragma unroll
    for (int j = 0; j < 4; j++) {
        float val = ldf(x + t + 256 * j);
        v[j] = val; s += val; ss = fmaf(val, val, ss);
    }
#pragma unroll
    for (int off = 32; off >= 1; off >>= 1) {
        s  += __shfl_down(s,  off, 64);
        ss += __shfl_down(ss, off, 64);
    }
    __shared__ float red[10];
    const int wave = t >> 6, lane = t & 63;
    if (lane == 0) { red[wave] = s; red[4 + wave] = ss; }
    __syncthreads();
    if (t == 0) {
        float S1 = red[0] + red[1] + red[2] + red[3];
        float S2 = red[4] + red[5] + red[6] + red[7];
        float mu = S1 / (float)D;
        float var = (S2 - (float)D * mu * mu) / (float)(D - 1);  // ddof=1
        float sig = sqrtf(fmaxf(var, 0.f)) + 1e-6f;              // eps on sigma
        red[8] = mu; red[9] = 1.f / sig;
    }
    __syncthreads();
    const float mu = red[8], rs = red[9];
#pragma unroll
    for (int j = 0; j < 4; j++) {
        int c = t + 256 * j;
        out[(size_t)row * D + c] = f2bu((v[j] - mu) * rs * ga[c] + gb[c]);
    }
}

// ======================= MFMA GEMM core (128x128 tile) =======================
#define GEMM_CORE(A_, B_, K_)                                                   \
    __shared__ u16 As[128 * 32];                                                \
    __shared__ u16 Bs[128 * 32];                                                \
    const int t = threadIdx.x;                                                  \
    const int w = t >> 6, l = t & 63;                                           \
    const int m0 = blockIdx.y * 128, n0 = blockIdx.x * 128;                     \
    const int qk = l >> 4, col = l & 15;                                        \
    const int wm = (w & 1) * 64, wn = (w >> 1) * 64;                            \
    const int sr  = l >> 2;                                                     \
    const int sq  = l & 3;                                                      \
    const int row = w * 16 + sr;                                                \
    const int gq  = sq ^ ((row >> 1) & 3);                                      \
    const u16* Ap = A_ + (size_t)(m0 + row) * K_ + gq * 8;                      \
    const u16* Bp = B_ + (size_t)(n0 + row) * K_ + gq * 8;                      \
    u16* AsW = As + w * 16 * 32;                                                \
    u16* BsW = Bs + w * 16 * 32;                                                \
    const int mloc = wm + col, nloc = wn + col;                                 \
    const u16* aBase = As + mloc * 32 + (qk ^ ((mloc >> 1) & 3)) * 8;           \
    const u16* bBase = Bs + nloc * 32 + (qk ^ ((nloc >> 1) & 3)) * 8;           \
    floatx4 acc[4][4];                                                          \
    _Pragma("unroll")                                                           \
    for (int i = 0; i < 4; i++)                                                 \
        _Pragma("unroll")                                                       \
        for (int j = 0; j < 4; j++) acc[i][j] = (floatx4)0.f;                   \
    for (int k0 = 0; k0 < K_; k0 += 32) {                                       \
        __syncthreads();                                                        \
        async16(Ap,                  AsW);                                      \
        async16(Ap + (size_t)64 * K_, AsW + 64 * 32);                           \
        async16(Bp,                  BsW);                                      \
        async16(Bp + (size_t)64 * K_, BsW + 64 * 32);                           \
        Ap += 32; Bp += 32;                                                     \
        __syncthreads();                                                        \
        short8 a[4], b[4];                                                      \
        _Pragma("unroll")                                                       \
        for (int i = 0; i < 4; i++) a[i] = *(const short8*)(aBase + i * 16 * 32);\
        _Pragma("unroll")                                                       \
        for (int j = 0; j < 4; j++) b[j] = *(const short8*)(bBase + j * 16 * 32);\
        _Pragma("unroll")                                                       \
        for (int i = 0; i < 4; i++)                                             \
            _Pragma("unroll")                                                   \
            for (int j = 0; j < 4; j++)                                         \
                acc[i][j] = __builtin_amdgcn_mfma_f32_16x16x32_bf16(            \
                    a[i], b[j], acc[i][j], 0, 0, 0);                            \
    }

// ---- generic GEMM 128x128 (+bias/relu/res), OMODE 0 f32 / 1 bf16 ------------
template <int OMODE, bool RELU, int RES>
__global__ __launch_bounds__(256, 2)
void gemm_mfma(const u16* __restrict__ A, const u16* __restrict__ B,
               const float* __restrict__ bias, const void* __restrict__ res,
               void* __restrict__ Cout, int M, int N, int K)
{
    GEMM_CORE(A, B, K)
#pragma unroll
    for (int j = 0; j < 4; j++) {
        const int n = n0 + wn + j * 16 + col;
        const float bn = bias[n];
#pragma unroll
        for (int i = 0; i < 4; i++) {
#pragma unroll
            for (int r = 0; r < 4; r++) {
                const int m = m0 + wm + i * 16 + qk * 4 + r;
                float v = acc[i][j][r] + bn;
                if (RELU) v = fmaxf(v, 0.f);
                if (RES == 1) v += ((const float*)res)[(size_t)m * N + n];
                if (RES == 2) v += bu2f(((const u16*)res)[(size_t)m * N + n]);
                if (OMODE == 0) ((float*)Cout)[(size_t)m * N + n] = v;
                if (OMODE == 1) ((u16*)Cout)[(size_t)m * N + n] = f2bu(v);
            }
        }
    }
}

// ---- fused QKV GEMM (128x128): outputs f16 Q [S,D], K [S,D], V^T [D,S] ------
__global__ __launch_bounds__(256, 2)
void gemm_qkv(const u16* __restrict__ A, const u16* __restrict__ B,
              const float* __restrict__ bq, const float* __restrict__ bk,
              const float* __restrict__ bv, u16* __restrict__ outQ,
              u16* __restrict__ outK, u16* __restrict__ outVT)
{
    const int K = D;
    GEMM_CORE(A, B, K)
    const int seg   = n0 >> 10;
    const int nbase = n0 & 1023;
    const float* bs = (seg == 0) ? bq : (seg == 1) ? bk : bv;
    u16* outMN = (seg == 0) ? outQ : outK;
#pragma unroll
    for (int j = 0; j < 4; j++) {
        const int nl = nbase + wn + j * 16 + col;
        const float bn = bs[nl];
#pragma unroll
        for (int i = 0; i < 4; i++) {
#pragma unroll
            for (int r = 0; r < 4; r++) {
                const int m = m0 + wm + i * 16 + qk * 4 + r;
                float v = acc[i][j][r] + bn;
                if (seg < 2) outMN[(size_t)m * D + nl] = f2h(v);
                else         outVT[(size_t)nl * S + m] = f2h(v);
            }
        }
    }
}

// ---- 128x64-tile GEMM (2x the blocks for N=1024 outputs: WO, FFN2) ----------
template <int OMODE, int RES>
__global__ __launch_bounds__(256, 2)
void gemm_mfma64(const u16* __restrict__ A, const u16* __restrict__ B,
                 const float* __restrict__ bias, const void* __restrict__ res,
                 void* __restrict__ Cout, int M, int N, int K)
{
    __shared__ u16 As[128 * 32];
    __shared__ u16 Bs[64 * 32];
    const int t = threadIdx.x;
    const int w = t >> 6, l = t & 63;
    const int m0 = blockIdx.y * 128, n0 = blockIdx.x * 64;
    const int qk = l >> 4, col = l & 15;
    const int wm = (w & 1) * 64, wn = (w >> 1) * 32;
    const int sr = l >> 2, sq = l & 3;
    const int row = w * 16 + sr;
    const int gq = sq ^ ((row >> 1) & 3);
    const u16* Ap = A + (size_t)(m0 + row) * K + gq * 8;
    const u16* Bp = B + (size_t)(n0 + row) * K + gq * 8;
    u16* AsW = As + w * 16 * 32;
    u16* BsW = Bs + w * 16 * 32;
    const int mloc = wm + col, nloc = wn + col;
    const u16* aBase = As + mloc * 32 + (qk ^ ((mloc >> 1) & 3)) * 8;
    const u16* bBase = Bs + nloc * 32 + (qk ^ ((nloc >> 1) & 3)) * 8;
    floatx4 acc[4][2];
#pragma unroll
    for (int i = 0; i < 4; i++)
#pragma unroll
        for (int j = 0; j < 2; j++) acc[i][j] = (floatx4)0.f;
    for (int k0 = 0; k0 < K; k0 += 32) {
        __syncthreads();
        async16(Ap, AsW);
        async16(Ap + (size_t)64 * K, AsW + 64 * 32);
        async16(Bp, BsW);
        Ap += 32; Bp += 32;
        __syncthreads();
        short8 a[4], b[2];
#pragma unroll
        for (int i = 0; i < 4; i++) a[i] = *(const short8*)(aBase + i * 16 * 32);
#pragma unroll
        for (int j = 0; j < 2; j++) b[j] = *(const short8*)(bBase + j * 16 * 32);
#pragma unroll
        for (int i = 0; i < 4; i++)
#pragma unroll
            for (int j = 0; j < 2; j++)
                acc[i][j] = __builtin_amdgcn_mfma_f32_16x16x32_bf16(
                    a[i], b[j], acc[i][j], 0, 0, 0);
    }
#pragma unroll
    for (int j = 0; j < 2; j++) {
        const int n = n0 + wn + j * 16 + col;
        const float bn = bias[n];
#pragma unroll
        for (int i = 0; i < 4; i++) {
#pragma unroll
            for (int r = 0; r < 4; r++) {
                const int m = m0 + wm + i * 16 + qk * 4 + r;
                float v = acc[i][j][r] + bn;
                if (RES == 1) v += ((const float*)res)[(size_t)m * N + n];
                if (RES == 2) v += bu2f(((const u16*)res)[(size_t)m * N + n]);
                if (OMODE == 0) ((float*)Cout)[(size_t)m * N + n] = v;
                if (OMODE == 1) ((u16*)Cout)[(size_t)m * N + n] = f2bu(v);
            }
        }
    }
}

// =================== f16 MFMA fused sparse attention =========================
// Block: 16 q-rows of one head, 4 waves, grid NH*128 = 2048.
// Wave w owns tiles T = 4i+w (key-interleaved) -> every 512-key chunk is
// self-contained. Scores packed f16 pairs in VGPRs (ALL loops over sf fully
// unrolled -> constant indices -> stays in VGPRs; round-7 spill lesson);
// Newton via pk-f16 + fdot2; P streamed via 18 KB swizzled LDS; PV MFMA.
__global__ __launch_bounds__(256, 3)
void attn_f16(const u16* __restrict__ qb, const u16* __restrict__ kb,
              const u16* __restrict__ vT, const int* __restrict__ mask,
              u16* __restrict__ att)
{
    __shared__ u16  Plds[16 * 544];     // [row][512+32 pad] f16, 8-key-block swizzle
    __shared__ float red[256];          // cross-wave reduce, double-buffered
    const int h  = blockIdx.x >> 7;
    const int q0 = (blockIdx.x & 127) * 16;
    const int t  = threadIdx.x;
    const int w  = t >> 6, l = t & 63;
    const int lg = l >> 4, lc = l & 15;

    // Q a-frags (f16): A[m=lc][k=lg*8+j], two K=32 halves of HD=64
    const u16* qp = qb + (size_t)(q0 + lc) * D + h * HD + lg * 8;
    const half8v aq0 = *(const half8v*)qp;
    const half8v aq1 = *(const half8v*)(qp + 32);

    half2v sf[4][16];   // rows lg*4+r, pair p holds tiles (2p, 2p+1) of this wave
    {
        const u16* kbase = kb + h * HD + lg * 8;
#pragma unroll 4
        for (int p = 0; p < 16; p++) {
            const int T0 = 8 * p + w;       // tile 4*(2p)+w
            const int T1 = T0 + 4;          // tile 4*(2p+1)+w
            const u16* kp0 = kbase + (size_t)(T0 * 16 + lc) * D;
            const u16* kp1 = kbase + (size_t)(T1 * 16 + lc) * D;
            floatx4 a0 = (floatx4)0.f, a1 = (floatx4)0.f;
            a0 = mfma_f16(aq0, *(const half8v*)kp0,        a0);
            a0 = mfma_f16(aq1, *(const half8v*)(kp0 + 32), a0);
            a1 = mfma_f16(aq0, *(const half8v*)kp1,        a1);
            a1 = mfma_f16(aq1, *(const half8v*)(kp1 + 32), a1);
            const int mk0 = mask[T0 * 16 + lc];
            const int mk1 = mask[T1 * 16 + lc];
            // scale = (1/sqrt(64))*(1/2 from entmax) = 0.0625; masked -> -3e4 (f16-safe)
#pragma unroll
            for (int r = 0; r < 4; r++) {
                float s0 = mk0 ? a0[r] * 0.0625f : -30000.f;
                float s1 = mk1 ? a1[r] * 0.0625f : -30000.f;
                sf[r][p] = pkrtz(s0, s1);
            }
        }
    }

    const half2v hz = {(_Float16)0.f, (_Float16)0.f};
    const half2v h1 = {(_Float16)1.f, (_Float16)1.f};
    float tau[4];

    // ---- row max -> tau0 = mx - 1 (monotone Newton start, g(tau0) >= 1) ----
    {
#pragma unroll
        for (int r = 0; r < 4; r++) {
            half2v mm = sf[r][0];
#pragma unroll
            for (int p = 1; p < 16; p++) mm = __builtin_elementwise_max(mm, sf[r][p]);
            float mx = fmaxf((float)mm[0], (float)mm[1]);
#pragma unroll
            for (int off = 1; off <= 8; off <<= 1)
                mx = fmaxf(mx, __shfl_xor(mx, off, 64));
            if (lc == 0) red[w * 32 + (lg * 4 + r) * 2] = mx;
        }
        __syncthreads();
#pragma unroll
        for (int r = 0; r < 4; r++) {
            const int rowi = (lg * 4 + r) * 2;
            float m = fmaxf(fmaxf(red[rowi], red[32 + rowi]),
                            fmaxf(red[64 + rowi], red[96 + rowi]));
            tau[r] = m - 1.0f;
        }
    }

    // ---- Newton on g(tau) = sum relu(x-tau)^2 = 1 : 10 iters, fdot2 kernel ----
    for (int it = 0; it < 10; it++) {
        const int pb = ((it + 1) & 1) * 128;
#pragma unroll
        for (int r = 0; r < 4; r++) {
            half2v t2 = pkrtz(tau[r], tau[r]);
            float s1 = 0.f, s2 = 0.f;
#pragma unroll
            for (int p = 0; p < 16; p++) {
                half2v dp = __builtin_elementwise_max(sf[r][p] - t2, hz);
                s1 = fdot2f(dp, h1, s1);
                s2 = fdot2f(dp, dp, s2);
            }
#pragma unroll
            for (int off = 1; off <= 8; off <<= 1) {
                s1 += __shfl_xor(s1, off, 64);
                s2 += __shfl_xor(s2, off, 64);
            }
            if (lc == 0) {
                red[pb + w * 32 + (lg * 4 + r) * 2]     = s1;
                red[pb + w * 32 + (lg * 4 + r) * 2 + 1] = s2;
            }
        }
        __syncthreads();
#pragma unroll
        for (int r = 0; r < 4; r++) {
            const int rowi = (lg * 4 + r) * 2;
            float S1 = red[pb + rowi] + red[pb + 32 + rowi]
                     + red[pb + 64 + rowi] + red[pb + 96 + rowi];
            float S2 = red[pb + 1 + rowi] + red[pb + 33 + rowi]
                     + red[pb + 65 + rowi] + red[pb + 97 + rowi];
            tau[r] += (S2 - 1.0f) / (2.0f * S1);   // S1 >= S2 >= 1-eps : safe
        }
    }

    half2v t2f[4];
#pragma unroll
    for (int r = 0; r < 4; r++) t2f[r] = pkrtz(tau[r], tau[r]);

    // ---- 4 chunks of 512 keys: P -> LDS (swizzled) -> PV MFMA accumulate ----
    // c-loop MUST be unrolled: sf[r][4*c+m] needs compile-time indices or the
    // whole sf array is demoted to scratch (round-7: 600 MB spill traffic).
    floatx4 oacc = (floatx4)0.f;
    const u16* vp = vT + (size_t)(h * HD + w * 16 + lc) * S + lg * 8;
#pragma unroll
    for (int c = 0; c < 4; c++) {
        if (c) __syncthreads();             // prior chunk's PV reads done
#pragma unroll
        for (int m = 0; m < 4; m++) {
            const int kl0 = 128 * m + 16 * w + lc;   // and kl0+64
            const int b0 = kl0 >> 3, b1 = b0 + 8;
            const int k7 = kl0 & 7;
#pragma unroll
            for (int r = 0; r < 4; r++) {
                half2v dp = __builtin_elementwise_max(sf[r][4 * c + m] - t2f[r], hz);
                half2v pp = dp * dp;
                u32 bits;
                __builtin_memcpy(&bits, &pp, 4);
                const int row = lg * 4 + r;
                const int x = (row >> 1) & 3;
                const int p0 = (b0 & ~3) | ((b0 & 3) ^ x);
                const int p1 = (b1 & ~3) | ((b1 & 3) ^ x);
                Plds[row * 544 + p0 * 8 + k7] = (u16)bits;
                Plds[row * 544 + p1 * 8 + k7] = (u16)(bits >> 16);
            }
        }
        __syncthreads();
        const u16* vpc = vp + 512 * c;
#pragma unroll
        for (int s = 0; s < 16; s++) {
            const int bb = 4 * s + lg;
            const int pbk = (bb & ~3) | ((bb & 3) ^ ((lc >> 1) & 3));
            half8v af = *(const half8v*)&Plds[lc * 544 + pbk * 8];
            half8v bf = *(const half8v*)(vpc + 32 * s);
            oacc = mfma_f16(af, bf, oacc);
        }
    }
#pragma unroll
    for (int r = 0; r < 4; r++)
        att[(size_t)(q0 + lg * 4 + r) * D + h * HD + w * 16 + lc] = f2bu(oacc[r]);
}

// ---------------- host side ---------------------------------------------------
extern "C" void kernel_launch(void* const* d_in, const int* in_sizes, int n_in,
                              void* d_out, int out_size, void* d_ws, size_t ws_size,
                              hipStream_t stream)
{
    const float* inp  = (const float*)d_in[0];
    const int*   mask = (const int*)d_in[1];
    const float* wq   = (const float*)d_in[2];
    const float* bq   = (const float*)d_in[3];
    const float* wk   = (const float*)d_in[4];
    const float* bk   = (const float*)d_in[5];
    const float* wv   = (const float*)d_in[6];
    const float* bv   = (const float*)d_in[7];
    const float* wo   = (const float*)d_in[8];
    const float* bo   = (const float*)d_in[9];
    const float* ln1a = (const float*)d_in[10];
    const float* ln1b = (const float*)d_in[11];
    const float* w1   = (const float*)d_in[12];
    const float* b1   = (const float*)d_in[13];
    const float* w2   = (const float*)d_in[14];
    const float* b2   = (const float*)d_in[15];
    const float* ln2a = (const float*)d_in[16];
    const float* ln2b = (const float*)d_in[17];

    const size_t MB = 1u << 20;
    char* w = (char*)d_ws;
    // 32 MB overlay (16-bit bufs unless noted):
    //  [0,8):  wqkvb(6MB) -> w1b (after QKV) -> w2b (after FFN1)
    //  [8,12): x1 -> att -> x2   (bf16)
    //  [12,16): qb_ (f16) -> yb (bf16)
    //  [16,20): kb_ (f16)  \
    //  [20,24): vTb (f16)   > dead after attn -> hb [16,32)
    //  [24,26): wob (bf16) /  (dead after WO, before FFN1 writes hb)
    u16* wqkvb = (u16*)(w + 0 * MB);
    u16* w1b   = (u16*)(w + 0 * MB);
    u16* w2b   = (u16*)(w + 0 * MB);
    u16* x1    = (u16*)(w + 8 * MB);
    u16* att   = x1;
    u16* x2    = x1;
    u16* qb_   = (u16*)(w + 12 * MB);
    u16* yb    = (u16*)(w + 12 * MB);
    u16* kb_   = (u16*)(w + 16 * MB);
    u16* vTb   = (u16*)(w + 20 * MB);
    u16* wob   = (u16*)(w + 24 * MB);
    u16* hb    = (u16*)(w + 16 * MB);
    float* outF = (float*)d_out;

    // 0. weight conversions: QKV concat + WO
    cvt_kernel<<<1024, 256, 0, stream>>>(wq, wqkvb,                   (D * D) / 4);
    cvt_kernel<<<1024, 256, 0, stream>>>(wk, wqkvb + 1024 * 1024,     (D * D) / 4);
    cvt_kernel<<<1024, 256, 0, stream>>>(wv, wqkvb + 2 * 1024 * 1024, (D * D) / 4);
    cvt_kernel<<<1024, 256, 0, stream>>>(wo, wob, (D * D) / 4);
    // 1. LN1 -> bf16
    ln_kernel<float><<<S, 256, 0, stream>>>(inp, ln1a, ln1b, x1);
    // 2. fused QKV projection -> f16 Q [S,D], K [S,D], V^T [D,S]
    gemm_qkv<<<dim3(3 * D / 128, S / 128), 256, 0, stream>>>(
        x1, wqkvb, bq, bk, bv, qb_, kb_, vTb);
    // 3. convert w1 (wqkvb dead)
    cvt_kernel<<<4096, 256, 0, stream>>>(w1, w1b, (DFF * D) / 4);
    // 4. f16 MFMA fused entmax attention -> att bf16 (over x1 slot)
    attn_f16<<<NH * (S / 16), 256, 0, stream>>>(qb_, kb_, vTb, mask, att);
    // 5. WO projection + residual(inp fp32) -> yb bf16  (256 blocks)
    gemm_mfma64<1, 1><<<dim3(D / 64, S / 128), 256, 0, stream>>>(
        att, wob, bo, inp, yb, S, D, D);
    // 6. LN2 -> x2 (att dead)
    ln_kernel<u16><<<S, 256, 0, stream>>>(yb, ln2a, ln2b, x2);
    // 7. FFN1 (+ReLU) -> hb bf16 (kb_/vTb/wob dead)
    gemm_mfma<1, true, 0><<<dim3(DFF / 128, S / 128), 256, 0, stream>>>(
        x2, w1b, b1, nullptr, hb, S, DFF, D);
    // 8. convert w2 (w1b dead)
    cvt_kernel<<<4096, 256, 0, stream>>>(w2, w2b, (DFF * D) / 4);
    // 9. FFN2 + residual(yb bf16) -> fp32 out  (256 blocks)
    gemm_mfma64<0, 2><<<dim3(D / 64, S / 128), 256, 0, stream>>>(
        hb, w2b, b2, yb, outF, S, D, DFF);
}

// Round 9
// 443.883 us; speedup vs baseline: 1.3478x; 1.3457x over previous
//
#include <hip/hip_runtime.h>
#include <hip/hip_bf16.h>

// Problem dims (fixed by setup_inputs)
#define S   2048
#define D   1024
#define DFF 4096
#define NH  16
#define HD  64

typedef unsigned short u16;
typedef unsigned int   u32;
typedef __attribute__((ext_vector_type(8))) short      short8;  // 8 bf16
typedef __attribute__((ext_vector_type(4))) float      floatx4; // MFMA C/D
typedef __attribute__((ext_vector_type(2))) _Float16   half2v;
typedef __attribute__((ext_vector_type(8))) _Float16   half8v;

__device__ __forceinline__ float bu2f(u16 u) {
    union { u32 i; float f; } x; x.i = ((u32)u) << 16; return x.f;
}
__device__ __forceinline__ u16 f2bu(float f) {
    __hip_bfloat16 h = __float2bfloat16(f);
    return *(u16*)&h;
}
__device__ __forceinline__ u16 f2h(float f) {
    _Float16 h = (_Float16)f; return *(u16*)&h;
}
__device__ __forceinline__ float ldf(const float* p) { return *p; }
__device__ __forceinline__ float ldf(const u16* p)   { return bu2f(*p); }

// cvt_pkrtz returns __fp16x2; bit-cast to our _Float16x2 (same 32-bit reg)
__device__ __forceinline__ half2v pkrtz(float a, float b) {
    auto v = __builtin_amdgcn_cvt_pkrtz(a, b);
    union { decltype(v) i; half2v o; } u; u.i = v; return u.o;
}

__device__ __forceinline__ floatx4 mfma_f16(half8v a, half8v b, floatx4 c) {
    return __builtin_amdgcn_mfma_f32_16x16x32_f16(a, b, c, 0, 0, 0);
}
__device__ __forceinline__ float fdot2f(half2v a, half2v b, float c) {
#if __has_builtin(__builtin_amdgcn_fdot2)
    return __builtin_amdgcn_fdot2(a, b, c, false);
#else
    return c + (float)a[0] * (float)b[0] + (float)a[1] * (float)b[1];
#endif
}

// async global->LDS, 16B per lane, lands at ldsbase + lane*16
__device__ __forceinline__ void async16(const void* g, void* l) {
    __builtin_amdgcn_global_load_lds(
        (const __attribute__((address_space(1))) u32*)g,
        (__attribute__((address_space(3))) u32*)l, 16, 0, 0);
}

// ---------------- fp32 -> bf16 bulk convert (weights) ------------------------
__global__ __launch_bounds__(256)
void cvt_kernel(const float* __restrict__ in, u16* __restrict__ out, int n4)
{
    int i = blockIdx.x * 256 + threadIdx.x;
    if (i < n4) {
        float4 v = ((const float4*)in)[i];
        ushort4 s;
        s.x = f2bu(v.x); s.y = f2bu(v.y); s.z = f2bu(v.z); s.w = f2bu(v.w);
        ((ushort4*)out)[i] = s;
    }
}

// ---------------- LayerNorm: one block per row, D=1024, 256 threads ----------
template <typename T>
__global__ __launch_bounds__(256, 4)
void ln_kernel(const T* __restrict__ in, const float* __restrict__ ga,
               const float* __restrict__ gb, u16* __restrict__ out)
{
    const int row = blockIdx.x;
    const int t = threadIdx.x;
    const T* x = in + (size_t)row * D;
    float v[4];
    float s = 0.f, ss = 0.f;
#pragma unroll
    for (int j = 0; j < 4; j++) {
        float val = ldf(x + t + 256 * j);
        v[j] = val; s += val; ss = fmaf(val, val, ss);
    }
#pragma unroll
    for (int off = 32; off >= 1; off >>= 1) {
        s  += __shfl_down(s,  off, 64);
        ss += __shfl_down(ss, off, 64);
    }
    __shared__ float red[10];
    const int wave = t >> 6, lane = t & 63;
    if (lane == 0) { red[wave] = s; red[4 + wave] = ss; }
    __syncthreads();
    if (t == 0) {
        float S1 = red[0] + red[1] + red[2] + red[3];
        float S2 = red[4] + red[5] + red[6] + red[7];
        float mu = S1 / (float)D;
        float var = (S2 - (float)D * mu * mu) / (float)(D - 1);  // ddof=1
        float sig = sqrtf(fmaxf(var, 0.f)) + 1e-6f;              // eps on sigma
        red[8] = mu; red[9] = 1.f / sig;
    }
    __syncthreads();
    const float mu = red[8], rs = red[9];
#pragma unroll
    for (int j = 0; j < 4; j++) {
        int c = t + 256 * j;
        out[(size_t)row * D + c] = f2bu((v[j] - mu) * rs * ga[c] + gb[c]);
    }
}

// ======================= MFMA GEMM core (128x128 tile) =======================
#define GEMM_CORE(A_, B_, K_)                                                   \
    __shared__ u16 As[128 * 32];                                                \
    __shared__ u16 Bs[128 * 32];                                                \
    const int t = threadIdx.x;                                                  \
    const int w = t >> 6, l = t & 63;                                           \
    const int m0 = blockIdx.y * 128, n0 = blockIdx.x * 128;                     \
    const int qk = l >> 4, col = l & 15;                                        \
    const int wm = (w & 1) * 64, wn = (w >> 1) * 64;                            \
    const int sr  = l >> 2;                                                     \
    const int sq  = l & 3;                                                      \
    const int row = w * 16 + sr;                                                \
    const int gq  = sq ^ ((row >> 1) & 3);                                      \
    const u16* Ap = A_ + (size_t)(m0 + row) * K_ + gq * 8;                      \
    const u16* Bp = B_ + (size_t)(n0 + row) * K_ + gq * 8;                      \
    u16* AsW = As + w * 16 * 32;                                                \
    u16* BsW = Bs + w * 16 * 32;                                                \
    const int mloc = wm + col, nloc = wn + col;                                 \
    const u16* aBase = As + mloc * 32 + (qk ^ ((mloc >> 1) & 3)) * 8;           \
    const u16* bBase = Bs + nloc * 32 + (qk ^ ((nloc >> 1) & 3)) * 8;           \
    floatx4 acc[4][4];                                                          \
    _Pragma("unroll")                                                           \
    for (int i = 0; i < 4; i++)                                                 \
        _Pragma("unroll")                                                       \
        for (int j = 0; j < 4; j++) acc[i][j] = (floatx4)0.f;                   \
    for (int k0 = 0; k0 < K_; k0 += 32) {                                       \
        __syncthreads();                                                        \
        async16(Ap,                  AsW);                                      \
        async16(Ap + (size_t)64 * K_, AsW + 64 * 32);                           \
        async16(Bp,                  BsW);                                      \
        async16(Bp + (size_t)64 * K_, BsW + 64 * 32);                           \
        Ap += 32; Bp += 32;                                                     \
        __syncthreads();                                                        \
        short8 a[4], b[4];                                                      \
        _Pragma("unroll")                                                       \
        for (int i = 0; i < 4; i++) a[i] = *(const short8*)(aBase + i * 16 * 32);\
        _Pragma("unroll")                                                       \
        for (int j = 0; j < 4; j++) b[j] = *(const short8*)(bBase + j * 16 * 32);\
        _Pragma("unroll")                                                       \
        for (int i = 0; i < 4; i++)                                             \
            _Pragma("unroll")                                                   \
            for (int j = 0; j < 4; j++)                                         \
                acc[i][j] = __builtin_amdgcn_mfma_f32_16x16x32_bf16(            \
                    a[i], b[j], acc[i][j], 0, 0, 0);                            \
    }

// ---- generic GEMM 128x128 (+bias/relu/res), OMODE 0 f32 / 1 bf16 ------------
template <int OMODE, bool RELU, int RES>
__global__ __launch_bounds__(256, 2)
void gemm_mfma(const u16* __restrict__ A, const u16* __restrict__ B,
               const float* __restrict__ bias, const void* __restrict__ res,
               void* __restrict__ Cout, int M, int N, int K)
{
    GEMM_CORE(A, B, K)
#pragma unroll
    for (int j = 0; j < 4; j++) {
        const int n = n0 + wn + j * 16 + col;
        const float bn = bias[n];
#pragma unroll
        for (int i = 0; i < 4; i++) {
#pragma unroll
            for (int r = 0; r < 4; r++) {
                const int m = m0 + wm + i * 16 + qk * 4 + r;
                float v = acc[i][j][r] + bn;
                if (RELU) v = fmaxf(v, 0.f);
                if (RES == 1) v += ((const float*)res)[(size_t)m * N + n];
                if (RES == 2) v += bu2f(((const u16*)res)[(size_t)m * N + n]);
                if (OMODE == 0) ((float*)Cout)[(size_t)m * N + n] = v;
                if (OMODE == 1) ((u16*)Cout)[(size_t)m * N + n] = f2bu(v);
            }
        }
    }
}

// ---- fused QKV GEMM (128x128): outputs f16 Q [S,D], K [S,D], V^T [D,S] ------
__global__ __launch_bounds__(256, 2)
void gemm_qkv(const u16* __restrict__ A, const u16* __restrict__ B,
              const float* __restrict__ bq, const float* __restrict__ bk,
              const float* __restrict__ bv, u16* __restrict__ outQ,
              u16* __restrict__ outK, u16* __restrict__ outVT)
{
    const int K = D;
    GEMM_CORE(A, B, K)
    const int seg   = n0 >> 10;
    const int nbase = n0 & 1023;
    const float* bs = (seg == 0) ? bq : (seg == 1) ? bk : bv;
    u16* outMN = (seg == 0) ? outQ : outK;
#pragma unroll
    for (int j = 0; j < 4; j++) {
        const int nl = nbase + wn + j * 16 + col;
        const float bn = bs[nl];
#pragma unroll
        for (int i = 0; i < 4; i++) {
#pragma unroll
            for (int r = 0; r < 4; r++) {
                const int m = m0 + wm + i * 16 + qk * 4 + r;
                float v = acc[i][j][r] + bn;
                if (seg < 2) outMN[(size_t)m * D + nl] = f2h(v);
                else         outVT[(size_t)nl * S + m] = f2h(v);
            }
        }
    }
}

// ---- 128x64-tile GEMM (2x the blocks for N=1024 outputs: WO, FFN2) ----------
template <int OMODE, int RES>
__global__ __launch_bounds__(256, 2)
void gemm_mfma64(const u16* __restrict__ A, const u16* __restrict__ B,
                 const float* __restrict__ bias, const void* __restrict__ res,
                 void* __restrict__ Cout, int M, int N, int K)
{
    __shared__ u16 As[128 * 32];
    __shared__ u16 Bs[64 * 32];
    const int t = threadIdx.x;
    const int w = t >> 6, l = t & 63;
    const int m0 = blockIdx.y * 128, n0 = blockIdx.x * 64;
    const int qk = l >> 4, col = l & 15;
    const int wm = (w & 1) * 64, wn = (w >> 1) * 32;
    const int sr = l >> 2, sq = l & 3;
    const int row = w * 16 + sr;
    const int gq = sq ^ ((row >> 1) & 3);
    const u16* Ap = A + (size_t)(m0 + row) * K + gq * 8;
    const u16* Bp = B + (size_t)(n0 + row) * K + gq * 8;
    u16* AsW = As + w * 16 * 32;
    u16* BsW = Bs + w * 16 * 32;
    const int mloc = wm + col, nloc = wn + col;
    const u16* aBase = As + mloc * 32 + (qk ^ ((mloc >> 1) & 3)) * 8;
    const u16* bBase = Bs + nloc * 32 + (qk ^ ((nloc >> 1) & 3)) * 8;
    floatx4 acc[4][2];
#pragma unroll
    for (int i = 0; i < 4; i++)
#pragma unroll
        for (int j = 0; j < 2; j++) acc[i][j] = (floatx4)0.f;
    for (int k0 = 0; k0 < K; k0 += 32) {
        __syncthreads();
        async16(Ap, AsW);
        async16(Ap + (size_t)64 * K, AsW + 64 * 32);
        async16(Bp, BsW);
        Ap += 32; Bp += 32;
        __syncthreads();
        short8 a[4], b[2];
#pragma unroll
        for (int i = 0; i < 4; i++) a[i] = *(const short8*)(aBase + i * 16 * 32);
#pragma unroll
        for (int j = 0; j < 2; j++) b[j] = *(const short8*)(bBase + j * 16 * 32);
#pragma unroll
        for (int i = 0; i < 4; i++)
#pragma unroll
            for (int j = 0; j < 2; j++)
                acc[i][j] = __builtin_amdgcn_mfma_f32_16x16x32_bf16(
                    a[i], b[j], acc[i][j], 0, 0, 0);
    }
#pragma unroll
    for (int j = 0; j < 2; j++) {
        const int n = n0 + wn + j * 16 + col;
        const float bn = bias[n];
#pragma unroll
        for (int i = 0; i < 4; i++) {
#pragma unroll
            for (int r = 0; r < 4; r++) {
                const int m = m0 + wm + i * 16 + qk * 4 + r;
                float v = acc[i][j][r] + bn;
                if (RES == 1) v += ((const float*)res)[(size_t)m * N + n];
                if (RES == 2) v += bu2f(((const u16*)res)[(size_t)m * N + n]);
                if (OMODE == 0) ((float*)Cout)[(size_t)m * N + n] = v;
                if (OMODE == 1) ((u16*)Cout)[(size_t)m * N + n] = f2bu(v);
            }
        }
    }
}

// =================== f16 MFMA fused sparse attention =========================
// Block: 16 q-rows of one head, 4 waves, grid NH*128 = 2048.
// Wave w owns tiles T = 4i+w (key-interleaved) -> every 512-key chunk is
// self-contained. Scores packed f16 pairs in VGPRs.
// SPILL RULE (rounds 7+8): EVERY loop touching sf[] must be FULLY unrolled —
// one runtime-indexed read OR WRITE demotes the whole array to scratch
// (r7: unrolled PV reads, still 135 MB scratch writes from the `unroll 4`
// score-store loop; WRITE_SIZE 135 MB == 2048*256*64reg*4B exactly).
__global__ __launch_bounds__(256, 3)
void attn_f16(const u16* __restrict__ qb, const u16* __restrict__ kb,
              const u16* __restrict__ vT, const int* __restrict__ mask,
              u16* __restrict__ att)
{
    __shared__ u16  Plds[16 * 544];     // [row][512+32 pad] f16, 8-key-block swizzle
    __shared__ float red[256];          // cross-wave reduce, double-buffered
    const int h  = blockIdx.x >> 7;
    const int q0 = (blockIdx.x & 127) * 16;
    const int t  = threadIdx.x;
    const int w  = t >> 6, l = t & 63;
    const int lg = l >> 4, lc = l & 15;

    // Q a-frags (f16): A[m=lc][k=lg*8+j], two K=32 halves of HD=64
    const u16* qp = qb + (size_t)(q0 + lc) * D + h * HD + lg * 8;
    const half8v aq0 = *(const half8v*)qp;
    const half8v aq1 = *(const half8v*)(qp + 32);

    half2v sf[4][16];   // rows lg*4+r, pair p holds tiles (2p, 2p+1) of this wave
    {
        const u16* kbase = kb + h * HD + lg * 8;
#pragma unroll            // FULL unroll: sf store index must be compile-time
        for (int p = 0; p < 16; p++) {
            const int T0 = 8 * p + w;       // tile 4*(2p)+w
            const int T1 = T0 + 4;          // tile 4*(2p+1)+w
            const u16* kp0 = kbase + (size_t)(T0 * 16 + lc) * D;
            const u16* kp1 = kbase + (size_t)(T1 * 16 + lc) * D;
            floatx4 a0 = (floatx4)0.f, a1 = (floatx4)0.f;
            a0 = mfma_f16(aq0, *(const half8v*)kp0,        a0);
            a0 = mfma_f16(aq1, *(const half8v*)(kp0 + 32), a0);
            a1 = mfma_f16(aq0, *(const half8v*)kp1,        a1);
            a1 = mfma_f16(aq1, *(const half8v*)(kp1 + 32), a1);
            const int mk0 = mask[T0 * 16 + lc];
            const int mk1 = mask[T1 * 16 + lc];
            // scale = (1/sqrt(64))*(1/2 from entmax) = 0.0625; masked -> -3e4 (f16-safe)
#pragma unroll
            for (int r = 0; r < 4; r++) {
                float s0 = mk0 ? a0[r] * 0.0625f : -30000.f;
                float s1 = mk1 ? a1[r] * 0.0625f : -30000.f;
                sf[r][p] = pkrtz(s0, s1);
            }
        }
    }

    const half2v hz = {(_Float16)0.f, (_Float16)0.f};
    const half2v h1 = {(_Float16)1.f, (_Float16)1.f};
    float tau[4];

    // ---- row max -> tau0 = mx - 1 (monotone Newton start, g(tau0) >= 1) ----
    {
#pragma unroll
        for (int r = 0; r < 4; r++) {
            half2v mm = sf[r][0];
#pragma unroll
            for (int p = 1; p < 16; p++) mm = __builtin_elementwise_max(mm, sf[r][p]);
            float mx = fmaxf((float)mm[0], (float)mm[1]);
#pragma unroll
            for (int off = 1; off <= 8; off <<= 1)
                mx = fmaxf(mx, __shfl_xor(mx, off, 64));
            if (lc == 0) red[w * 32 + (lg * 4 + r) * 2] = mx;
        }
        __syncthreads();
#pragma unroll
        for (int r = 0; r < 4; r++) {
            const int rowi = (lg * 4 + r) * 2;
            float m = fmaxf(fmaxf(red[rowi], red[32 + rowi]),
                            fmaxf(red[64 + rowi], red[96 + rowi]));
            tau[r] = m - 1.0f;
        }
    }

    // ---- Newton on g(tau) = sum relu(x-tau)^2 = 1 : 10 iters, fdot2 kernel ----
    for (int it = 0; it < 10; it++) {
        const int pb = ((it + 1) & 1) * 128;
#pragma unroll
        for (int r = 0; r < 4; r++) {
            half2v t2 = pkrtz(tau[r], tau[r]);
            float s1 = 0.f, s2 = 0.f;
#pragma unroll
            for (int p = 0; p < 16; p++) {
                half2v dp = __builtin_elementwise_max(sf[r][p] - t2, hz);
                s1 = fdot2f(dp, h1, s1);
                s2 = fdot2f(dp, dp, s2);
            }
#pragma unroll
            for (int off = 1; off <= 8; off <<= 1) {
                s1 += __shfl_xor(s1, off, 64);
                s2 += __shfl_xor(s2, off, 64);
            }
            if (lc == 0) {
                red[pb + w * 32 + (lg * 4 + r) * 2]     = s1;
                red[pb + w * 32 + (lg * 4 + r) * 2 + 1] = s2;
            }
        }
        __syncthreads();
#pragma unroll
        for (int r = 0; r < 4; r++) {
            const int rowi = (lg * 4 + r) * 2;
            float S1 = red[pb + rowi] + red[pb + 32 + rowi]
                     + red[pb + 64 + rowi] + red[pb + 96 + rowi];
            float S2 = red[pb + 1 + rowi] + red[pb + 33 + rowi]
                     + red[pb + 65 + rowi] + red[pb + 97 + rowi];
            tau[r] += (S2 - 1.0f) / (2.0f * S1);   // S1 >= S2 >= 1-eps : safe
        }
    }

    half2v t2f[4];
#pragma unroll
    for (int r = 0; r < 4; r++) t2f[r] = pkrtz(tau[r], tau[r]);

    // ---- 4 chunks of 512 keys: P -> LDS (swizzled) -> PV MFMA accumulate ----
    floatx4 oacc = (floatx4)0.f;
    const u16* vp = vT + (size_t)(h * HD + w * 16 + lc) * S + lg * 8;
#pragma unroll            // FULL unroll: sf read index must be compile-time
    for (int c = 0; c < 4; c++) {
        if (c) __syncthreads();             // prior chunk's PV reads done
#pragma unroll
        for (int m = 0; m < 4; m++) {
            const int kl0 = 128 * m + 16 * w + lc;   // and kl0+64
            const int b0 = kl0 >> 3, b1 = b0 + 8;
            const int k7 = kl0 & 7;
#pragma unroll
            for (int r = 0; r < 4; r++) {
                half2v dp = __builtin_elementwise_max(sf[r][4 * c + m] - t2f[r], hz);
                half2v pp = dp * dp;
                u32 bits;
                __builtin_memcpy(&bits, &pp, 4);
                const int row = lg * 4 + r;
                const int x = (row >> 1) & 3;
                const int p0 = (b0 & ~3) | ((b0 & 3) ^ x);
                const int p1 = (b1 & ~3) | ((b1 & 3) ^ x);
                Plds[row * 544 + p0 * 8 + k7] = (u16)bits;
                Plds[row * 544 + p1 * 8 + k7] = (u16)(bits >> 16);
            }
        }
        __syncthreads();
        const u16* vpc = vp + 512 * c;
#pragma unroll
        for (int s = 0; s < 16; s++) {
            const int bb = 4 * s + lg;
            const int pbk = (bb & ~3) | ((bb & 3) ^ ((lc >> 1) & 3));
            half8v af = *(const half8v*)&Plds[lc * 544 + pbk * 8];
            half8v bf = *(const half8v*)(vpc + 32 * s);
            oacc = mfma_f16(af, bf, oacc);
        }
    }
#pragma unroll
    for (int r = 0; r < 4; r++)
        att[(size_t)(q0 + lg * 4 + r) * D + h * HD + w * 16 + lc] = f2bu(oacc[r]);
}

// ---------------- host side ---------------------------------------------------
extern "C" void kernel_launch(void* const* d_in, const int* in_sizes, int n_in,
                              void* d_out, int out_size, void* d_ws, size_t ws_size,
                              hipStream_t stream)
{
    const float* inp  = (const float*)d_in[0];
    const int*   mask = (const int*)d_in[1];
    const float* wq   = (const float*)d_in[2];
    const float* bq   = (const float*)d_in[3];
    const float* wk   = (const float*)d_in[4];
    const float* bk   = (const float*)d_in[5];
    const float* wv   = (const float*)d_in[6];
    const float* bv   = (const float*)d_in[7];
    const float* wo   = (const float*)d_in[8];
    const float* bo   = (const float*)d_in[9];
    const float* ln1a = (const float*)d_in[10];
    const float* ln1b = (const float*)d_in[11];
    const float* w1   = (const float*)d_in[12];
    const float* b1   = (const float*)d_in[13];
    const float* w2   = (const float*)d_in[14];
    const float* b2   = (const float*)d_in[15];
    const float* ln2a = (const float*)d_in[16];
    const float* ln2b = (const float*)d_in[17];

    const size_t MB = 1u << 20;
    char* w = (char*)d_ws;
    // 32 MB overlay (16-bit bufs unless noted):
    //  [0,8):  wqkvb(6MB) -> w1b (after QKV) -> w2b (after FFN1)
    //  [8,12): x1 -> att -> x2   (bf16)
    //  [12,16): qb_ (f16) -> yb (bf16)
    //  [16,20): kb_ (f16)  \
    //  [20,24): vTb (f16)   > dead after attn -> hb [16,32)
    //  [24,26): wob (bf16) /  (dead after WO, before FFN1 writes hb)
    u16* wqkvb = (u16*)(w + 0 * MB);
    u16* w1b   = (u16*)(w + 0 * MB);
    u16* w2b   = (u16*)(w + 0 * MB);
    u16* x1    = (u16*)(w + 8 * MB);
    u16* att   = x1;
    u16* x2    = x1;
    u16* qb_   = (u16*)(w + 12 * MB);
    u16* yb    = (u16*)(w + 12 * MB);
    u16* kb_   = (u16*)(w + 16 * MB);
    u16* vTb   = (u16*)(w + 20 * MB);
    u16* wob   = (u16*)(w + 24 * MB);
    u16* hb    = (u16*)(w + 16 * MB);
    float* outF = (float*)d_out;

    // 0. weight conversions: QKV concat + WO
    cvt_kernel<<<1024, 256, 0, stream>>>(wq, wqkvb,                   (D * D) / 4);
    cvt_kernel<<<1024, 256, 0, stream>>>(wk, wqkvb + 1024 * 1024,     (D * D) / 4);
    cvt_kernel<<<1024, 256, 0, stream>>>(wv, wqkvb + 2 * 1024 * 1024, (D * D) / 4);
    cvt_kernel<<<1024, 256, 0, stream>>>(wo, wob, (D * D) / 4);
    // 1. LN1 -> bf16
    ln_kernel<float><<<S, 256, 0, stream>>>(inp, ln1a, ln1b, x1);
    // 2. fused QKV projection -> f16 Q [S,D], K [S,D], V^T [D,S]
    gemm_qkv<<<dim3(3 * D / 128, S / 128), 256, 0, stream>>>(
        x1, wqkvb, bq, bk, bv, qb_, kb_, vTb);
    // 3. convert w1 (wqkvb dead)
    cvt_kernel<<<4096, 256, 0, stream>>>(w1, w1b, (DFF * D) / 4);
    // 4. f16 MFMA fused entmax attention -> att bf16 (over x1 slot)
    attn_f16<<<NH * (S / 16), 256, 0, stream>>>(qb_, kb_, vTb, mask, att);
    // 5. WO projection + residual(inp fp32) -> yb bf16  (256 blocks)
    gemm_mfma64<1, 1><<<dim3(D / 64, S / 128), 256, 0, stream>>>(
        att, wob, bo, inp, yb, S, D, D);
    // 6. LN2 -> x2 (att dead)
    ln_kernel<u16><<<S, 256, 0, stream>>>(yb, ln2a, ln2b, x2);
    // 7. FFN1 (+ReLU) -> hb bf16 (kb_/vTb/wob dead)
    gemm_mfma<1, true, 0><<<dim3(DFF / 128, S / 128), 256, 0, stream>>>(
        x2, w1b, b1, nullptr, hb, S, DFF, D);
    // 8. convert w2 (w1b dead)
    cvt_kernel<<<4096, 256, 0, stream>>>(w2, w2b, (DFF * D) / 4);
    // 9. FFN2 + residual(yb bf16) -> fp32 out  (256 blocks)
    gemm_mfma64<0, 2><<<dim3(D / 64, S / 128), 256, 0, stream>>>(
        hb, w2b, b2, yb, outF, S, D, DFF);
}

// Round 10
// 418.891 us; speedup vs baseline: 1.4283x; 1.0597x over previous
//
#include <hip/hip_runtime.h>
#include <hip/hip_bf16.h>

// Problem dims (fixed by setup_inputs)
#define S   2048
#define D   1024
#define DFF 4096
#define NH  16
#define HD  64

typedef unsigned short u16;
typedef unsigned int   u32;
typedef __attribute__((ext_vector_type(8))) short      short8;  // 8 bf16
typedef __attribute__((ext_vector_type(4))) float      floatx4; // MFMA C/D
typedef __attribute__((ext_vector_type(2))) _Float16   half2v;
typedef __attribute__((ext_vector_type(4))) _Float16   half4v;
typedef __attribute__((ext_vector_type(8))) _Float16   half8v;

__device__ __forceinline__ float bu2f(u16 u) {
    union { u32 i; float f; } x; x.i = ((u32)u) << 16; return x.f;
}
__device__ __forceinline__ u16 f2bu(float f) {
    __hip_bfloat16 h = __float2bfloat16(f);
    return *(u16*)&h;
}
__device__ __forceinline__ u16 f2h(float f) {
    _Float16 h = (_Float16)f; return *(u16*)&h;
}
__device__ __forceinline__ float ldf(const float* p) { return *p; }
__device__ __forceinline__ float ldf(const u16* p)   { return bu2f(*p); }

// cvt_pkrtz returns __fp16x2; bit-cast to our _Float16x2 (same 32-bit reg)
__device__ __forceinline__ half2v pkrtz(float a, float b) {
    auto v = __builtin_amdgcn_cvt_pkrtz(a, b);
    union { decltype(v) i; half2v o; } u; u.i = v; return u.o;
}

__device__ __forceinline__ floatx4 mfma_f16(half8v a, half8v b, floatx4 c) {
    return __builtin_amdgcn_mfma_f32_16x16x32_f16(a, b, c, 0, 0, 0);
}
__device__ __forceinline__ float fdot2f(half2v a, half2v b, float c) {
#if __has_builtin(__builtin_amdgcn_fdot2)
    return __builtin_amdgcn_fdot2(a, b, c, false);
#else
    return c + (float)a[0] * (float)b[0] + (float)a[1] * (float)b[1];
#endif
}

// async global->LDS, 16B per lane, lands at ldsbase + lane*16
__device__ __forceinline__ void async16(const void* g, void* l) {
    __builtin_amdgcn_global_load_lds(
        (const __attribute__((address_space(1))) u32*)g,
        (__attribute__((address_space(3))) u32*)l, 16, 0, 0);
}

// ---------------- fp32 -> bf16 bulk convert (weights) ------------------------
__global__ __launch_bounds__(256)
void cvt_kernel(const float* __restrict__ in, u16* __restrict__ out, int n4)
{
    int i = blockIdx.x * 256 + threadIdx.x;
    if (i < n4) {
        float4 v = ((const float4*)in)[i];
        ushort4 s;
        s.x = f2bu(v.x); s.y = f2bu(v.y); s.z = f2bu(v.z); s.w = f2bu(v.w);
        ((ushort4*)out)[i] = s;
    }
}

// ---------------- LayerNorm: one block per row, D=1024, 256 threads ----------
template <typename T>
__global__ __launch_bounds__(256, 4)
void ln_kernel(const T* __restrict__ in, const float* __restrict__ ga,
               const float* __restrict__ gb, u16* __restrict__ out)
{
    const int row = blockIdx.x;
    const int t = threadIdx.x;
    const T* x = in + (size_t)row * D;
    float v[4];
    float s = 0.f, ss = 0.f;
#pragma unroll
    for (int j = 0; j < 4; j++) {
        float val = ldf(x + t + 256 * j);
        v[j] = val; s += val; ss = fmaf(val, val, ss);
    }
#pragma unroll
    for (int off = 32; off >= 1; off >>= 1) {
        s  += __shfl_down(s,  off, 64);
        ss += __shfl_down(ss, off, 64);
    }
    __shared__ float red[10];
    const int wave = t >> 6, lane = t & 63;
    if (lane == 0) { red[wave] = s; red[4 + wave] = ss; }
    __syncthreads();
    if (t == 0) {
        float S1 = red[0] + red[1] + red[2] + red[3];
        float S2 = red[4] + red[5] + red[6] + red[7];
        float mu = S1 / (float)D;
        float var = (S2 - (float)D * mu * mu) / (float)(D - 1);  // ddof=1
        float sig = sqrtf(fmaxf(var, 0.f)) + 1e-6f;              // eps on sigma
        red[8] = mu; red[9] = 1.f / sig;
    }
    __syncthreads();
    const float mu = red[8], rs = red[9];
#pragma unroll
    for (int j = 0; j < 4; j++) {
        int c = t + 256 * j;
        out[(size_t)row * D + c] = f2bu((v[j] - mu) * rs * ga[c] + gb[c]);
    }
}

// ======================= MFMA GEMM core (128x128 tile) =======================
#define GEMM_CORE(A_, B_, K_)                                                   \
    __shared__ u16 As[128 * 32];                                                \
    __shared__ u16 Bs[128 * 32];                                                \
    const int t = threadIdx.x;                                                  \
    const int w = t >> 6, l = t & 63;                                           \
    const int m0 = blockIdx.y * 128, n0 = blockIdx.x * 128;                     \
    const int qk = l >> 4, col = l & 15;                                        \
    const int wm = (w & 1) * 64, wn = (w >> 1) * 64;                            \
    const int sr  = l >> 2;                                                     \
    const int sq  = l & 3;                                                      \
    const int row = w * 16 + sr;                                                \
    const int gq  = sq ^ ((row >> 1) & 3);                                      \
    const u16* Ap = A_ + (size_t)(m0 + row) * K_ + gq * 8;                      \
    const u16* Bp = B_ + (size_t)(n0 + row) * K_ + gq * 8;                      \
    u16* AsW = As + w * 16 * 32;                                                \
    u16* BsW = Bs + w * 16 * 32;                                                \
    const int mloc = wm + col, nloc = wn + col;                                 \
    const u16* aBase = As + mloc * 32 + (qk ^ ((mloc >> 1) & 3)) * 8;           \
    const u16* bBase = Bs + nloc * 32 + (qk ^ ((nloc >> 1) & 3)) * 8;           \
    floatx4 acc[4][4];                                                          \
    _Pragma("unroll")                                                           \
    for (int i = 0; i < 4; i++)                                                 \
        _Pragma("unroll")                                                       \
        for (int j = 0; j < 4; j++) acc[i][j] = (floatx4)0.f;                   \
    for (int k0 = 0; k0 < K_; k0 += 32) {                                       \
        __syncthreads();                                                        \
        async16(Ap,                  AsW);                                      \
        async16(Ap + (size_t)64 * K_, AsW + 64 * 32);                           \
        async16(Bp,                  BsW);                                      \
        async16(Bp + (size_t)64 * K_, BsW + 64 * 32);                           \
        Ap += 32; Bp += 32;                                                     \
        __syncthreads();                                                        \
        short8 a[4], b[4];                                                      \
        _Pragma("unroll")                                                       \
        for (int i = 0; i < 4; i++) a[i] = *(const short8*)(aBase + i * 16 * 32);\
        _Pragma("unroll")                                                       \
        for (int j = 0; j < 4; j++) b[j] = *(const short8*)(bBase + j * 16 * 32);\
        _Pragma("unroll")                                                       \
        for (int i = 0; i < 4; i++)                                             \
            _Pragma("unroll")                                                   \
            for (int j = 0; j < 4; j++)                                         \
                acc[i][j] = __builtin_amdgcn_mfma_f32_16x16x32_bf16(            \
                    a[i], b[j], acc[i][j], 0, 0, 0);                            \
    }

// ---- generic GEMM 128x128 (+bias/relu/res), OMODE 0 f32 / 1 bf16 ------------
template <int OMODE, bool RELU, int RES>
__global__ __launch_bounds__(256, 2)
void gemm_mfma(const u16* __restrict__ A, const u16* __restrict__ B,
               const float* __restrict__ bias, const void* __restrict__ res,
               void* __restrict__ Cout, int M, int N, int K)
{
    GEMM_CORE(A, B, K)
#pragma unroll
    for (int j = 0; j < 4; j++) {
        const int n = n0 + wn + j * 16 + col;
        const float bn = bias[n];
#pragma unroll
        for (int i = 0; i < 4; i++) {
#pragma unroll
            for (int r = 0; r < 4; r++) {
                const int m = m0 + wm + i * 16 + qk * 4 + r;
                float v = acc[i][j][r] + bn;
                if (RELU) v = fmaxf(v, 0.f);
                if (RES == 1) v += ((const float*)res)[(size_t)m * N + n];
                if (RES == 2) v += bu2f(((const u16*)res)[(size_t)m * N + n]);
                if (OMODE == 0) ((float*)Cout)[(size_t)m * N + n] = v;
                if (OMODE == 1) ((u16*)Cout)[(size_t)m * N + n] = f2bu(v);
            }
        }
    }
}

// ---- fused QKV GEMM (128x128): outputs f16 Q [S,D], K [S,D], V^T [D,S] ------
__global__ __launch_bounds__(256, 2)
void gemm_qkv(const u16* __restrict__ A, const u16* __restrict__ B,
              const float* __restrict__ bq, const float* __restrict__ bk,
              const float* __restrict__ bv, u16* __restrict__ outQ,
              u16* __restrict__ outK, u16* __restrict__ outVT)
{
    const int K = D;
    GEMM_CORE(A, B, K)
    const int seg   = n0 >> 10;
    const int nbase = n0 & 1023;
    const float* bs = (seg == 0) ? bq : (seg == 1) ? bk : bv;
    u16* outMN = (seg == 0) ? outQ : outK;
#pragma unroll
    for (int j = 0; j < 4; j++) {
        const int nl = nbase + wn + j * 16 + col;
        const float bn = bs[nl];
#pragma unroll
        for (int i = 0; i < 4; i++) {
#pragma unroll
            for (int r = 0; r < 4; r++) {
                const int m = m0 + wm + i * 16 + qk * 4 + r;
                float v = acc[i][j][r] + bn;
                if (seg < 2) outMN[(size_t)m * D + nl] = f2h(v);
                else         outVT[(size_t)nl * S + m] = f2h(v);
            }
        }
    }
}

// ---- 128x64-tile GEMM (2x the blocks for N=1024 outputs: WO, FFN2) ----------
template <int OMODE, int RES>
__global__ __launch_bounds__(256, 2)
void gemm_mfma64(const u16* __restrict__ A, const u16* __restrict__ B,
                 const float* __restrict__ bias, const void* __restrict__ res,
                 void* __restrict__ Cout, int M, int N, int K)
{
    __shared__ u16 As[128 * 32];
    __shared__ u16 Bs[64 * 32];
    const int t = threadIdx.x;
    const int w = t >> 6, l = t & 63;
    const int m0 = blockIdx.y * 128, n0 = blockIdx.x * 64;
    const int qk = l >> 4, col = l & 15;
    const int wm = (w & 1) * 64, wn = (w >> 1) * 32;
    const int sr = l >> 2, sq = l & 3;
    const int row = w * 16 + sr;
    const int gq = sq ^ ((row >> 1) & 3);
    const u16* Ap = A + (size_t)(m0 + row) * K + gq * 8;
    const u16* Bp = B + (size_t)(n0 + row) * K + gq * 8;
    u16* AsW = As + w * 16 * 32;
    u16* BsW = Bs + w * 16 * 32;
    const int mloc = wm + col, nloc = wn + col;
    const u16* aBase = As + mloc * 32 + (qk ^ ((mloc >> 1) & 3)) * 8;
    const u16* bBase = Bs + nloc * 32 + (qk ^ ((nloc >> 1) & 3)) * 8;
    floatx4 acc[4][2];
#pragma unroll
    for (int i = 0; i < 4; i++)
#pragma unroll
        for (int j = 0; j < 2; j++) acc[i][j] = (floatx4)0.f;
    for (int k0 = 0; k0 < K; k0 += 32) {
        __syncthreads();
        async16(Ap, AsW);
        async16(Ap + (size_t)64 * K, AsW + 64 * 32);
        async16(Bp, BsW);
        Ap += 32; Bp += 32;
        __syncthreads();
        short8 a[4], b[2];
#pragma unroll
        for (int i = 0; i < 4; i++) a[i] = *(const short8*)(aBase + i * 16 * 32);
#pragma unroll
        for (int j = 0; j < 2; j++) b[j] = *(const short8*)(bBase + j * 16 * 32);
#pragma unroll
        for (int i = 0; i < 4; i++)
#pragma unroll
            for (int j = 0; j < 2; j++)
                acc[i][j] = __builtin_amdgcn_mfma_f32_16x16x32_bf16(
                    a[i], b[j], acc[i][j], 0, 0, 0);
    }
#pragma unroll
    for (int j = 0; j < 2; j++) {
        const int n = n0 + wn + j * 16 + col;
        const float bn = bias[n];
#pragma unroll
        for (int i = 0; i < 4; i++) {
#pragma unroll
            for (int r = 0; r < 4; r++) {
                const int m = m0 + wm + i * 16 + qk * 4 + r;
                float v = acc[i][j][r] + bn;
                if (RES == 1) v += ((const float*)res)[(size_t)m * N + n];
                if (RES == 2) v += bu2f(((const u16*)res)[(size_t)m * N + n]);
                if (OMODE == 0) ((float*)Cout)[(size_t)m * N + n] = v;
                if (OMODE == 1) ((u16*)Cout)[(size_t)m * N + n] = f2bu(v);
            }
        }
    }
}

// =================== f16 MFMA fused sparse attention v2 ======================
// Block: 16 q-rows of one head, 4 waves, grid NH*128 = 2048.
// QK^T with SWAPPED operands: mfma(K,Q) -> D[m=key][n=qrow]: lane holds ONE
// q-row (lc), 4 adjacent keys per tile -> b64 transpose writes.
// LDS transpose (two 32 KB halves) -> lane (w,rho,c) owns row 4w+rho with 128
// keys in regs -> Newton is wave-local: 4-step 16-lane shuffle, ZERO barriers.
// P written in-place to the same swizzled slots; PV MFMA per half.
// Swizzle p = b ^ ((b>>3)&7) ^ (row&7) balances banks for all 4 patterns.
// SPILL RULE (r7/r8): every loop touching reg arrays fully unrolled.
__global__ __launch_bounds__(256, 3)
void attn_f16(const u16* __restrict__ qb, const u16* __restrict__ kb,
              const u16* __restrict__ vT, const int* __restrict__ mask,
              u16* __restrict__ att)
{
    __shared__ u16 Plds[16 * 1024];     // 32 KB: one 1024-key half (scores, then P)
    const int hh = blockIdx.x >> 7;
    const int q0 = (blockIdx.x & 127) * 16;
    const int t  = threadIdx.x;
    const int w  = t >> 6, l = t & 63;
    const int lg = l >> 4, lc = l & 15;

    // Q as B-operand: B[n=lc (q-row)][k=lg*8+j]
    const u16* qp = qb + (size_t)(q0 + lc) * D + hh * HD + lg * 8;
    const half8v bq0 = *(const half8v*)qp;
    const half8v bq1 = *(const half8v*)(qp + 32);

    // ---- QK^T swapped: wave w owns keys [512w, 512w+512), 32 tiles ----
    // lane: q-row = lc, keys = 512w + T*16 + lg*4 + r  (4 ADJACENT keys)
    half4v sc[32];
    const int keyw = w * 512;
    {
        const u16* kbase = kb + hh * HD + lg * 8;
#pragma unroll
        for (int T = 0; T < 32; T++) {
            const u16* kp = kbase + (size_t)(keyw + T * 16 + lc) * D;
            floatx4 a = (floatx4)0.f;
            a = mfma_f16(*(const half8v*)kp,        bq0, a);   // A = K !
            a = mfma_f16(*(const half8v*)(kp + 32), bq1, a);
            const int4 mk = *(const int4*)(mask + keyw + T * 16 + lg * 4);
            // scale = (1/sqrt(64))*(1/2 entmax) = 0.0625; masked -> -3e4 (f16-safe)
            half2v p01 = pkrtz(mk.x ? a[0] * 0.0625f : -30000.f,
                               mk.y ? a[1] * 0.0625f : -30000.f);
            half2v p23 = pkrtz(mk.z ? a[2] * 0.0625f : -30000.f,
                               mk.w ? a[3] * 0.0625f : -30000.f);
            sc[T] = __builtin_shufflevector(p01, p23, 0, 1, 2, 3);
        }
    }

    // ---- LDS transpose, two halves; target: lane owns row R, keys
    //      {1024h + lc*64 + o : o in [0,64)} per half, as half8v xq[16] ----
    const int R = 4 * w + lg;           // row this lane owns post-transpose
    half8v xq[16];
#pragma unroll
    for (int h = 0; h < 2; h++) {
        if ((w >> 1) == h) {            // this wave's keys live in half h
#pragma unroll
            for (int T = 0; T < 32; T++) {
                const int kl = (w & 1) * 512 + T * 16 + lg * 4;  // local key
                const int b  = kl >> 3;
                const int p  = b ^ ((b >> 3) & 7) ^ (lc & 7);
                *(half4v*)&Plds[lc * 1024 + p * 8 + (lg & 1) * 4] = sc[T];
            }
        }
        __syncthreads();
#pragma unroll
        for (int s = 0; s < 8; s++) {
            const int b = lc * 8 + s;
            const int p = b ^ ((b >> 3) & 7) ^ (R & 7);
            xq[h * 8 + s] = *(const half8v*)&Plds[R * 1024 + p * 8];
        }
        __syncthreads();
    }

    // ---- row max (wave-local: in-lane + 4-step 16-lane butterfly) ----
    float tau;
    {
        half8v m8 = xq[0];
#pragma unroll
        for (int i = 1; i < 16; i++) m8 = __builtin_elementwise_max(m8, xq[i]);
        union { half8v v; half2v h[4]; } u; u.v = m8;
        half2v m2 = __builtin_elementwise_max(
            __builtin_elementwise_max(u.h[0], u.h[1]),
            __builtin_elementwise_max(u.h[2], u.h[3]));
        float mx = fmaxf((float)m2[0], (float)m2[1]);
#pragma unroll
        for (int off = 1; off <= 8; off <<= 1)
            mx = fmaxf(mx, __shfl_xor(mx, off, 64));
        tau = mx - 1.0f;                // g(tau0) >= 1 -> monotone Newton
    }

    // ---- Newton, 10 iters, ZERO barriers: g(tau) = sum relu(x-tau)^2 = 1 ----
    const half8v z8 = (half8v)(_Float16)0.f;
    const half2v one2 = {(_Float16)1.f, (_Float16)1.f};
#pragma unroll 1
    for (int it = 0; it < 10; it++) {
        const _Float16 th = (_Float16)tau;
        const half8v t8 = {th, th, th, th, th, th, th, th};
        float s1a = 0.f, s1b = 0.f, s2a = 0.f, s2b = 0.f;
#pragma unroll
        for (int i = 0; i < 16; i++) {
            union { half8v v; half2v h[4]; } u;
            u.v = __builtin_elementwise_max(xq[i] - t8, z8);
            s1a = fdot2f(u.h[0], one2, s1a);
            s2a = fdot2f(u.h[0], u.h[0], s2a);
            s1b = fdot2f(u.h[1], one2, s1b);
            s2b = fdot2f(u.h[1], u.h[1], s2b);
            s1a = fdot2f(u.h[2], one2, s1a);
            s2a = fdot2f(u.h[2], u.h[2], s2a);
            s1b = fdot2f(u.h[3], one2, s1b);
            s2b = fdot2f(u.h[3], u.h[3], s2b);
        }
        float s1 = s1a + s1b, s2 = s2a + s2b;
#pragma unroll
        for (int off = 1; off <= 8; off <<= 1) {
            s1 += __shfl_xor(s1, off, 64);
            s2 += __shfl_xor(s2, off, 64);
        }
        tau += (s2 - 1.0f) / (2.0f * fmaxf(s1, 1e-4f));
    }

    // ---- P = relu(x-tau)^2 in-place (same slots this lane read) + PV ----
    const _Float16 th = (_Float16)tau;
    const half8v t8 = {th, th, th, th, th, th, th, th};
    floatx4 oacc = (floatx4)0.f;
    const u16* vp = vT + (size_t)(hh * HD + w * 16 + lc) * S + lg * 8;
#pragma unroll
    for (int h = 0; h < 2; h++) {
#pragma unroll
        for (int s = 0; s < 8; s++) {
            half8v dp = __builtin_elementwise_max(xq[h * 8 + s] - t8, z8);
            const int b = lc * 8 + s;
            const int p = b ^ ((b >> 3) & 7) ^ (R & 7);
            *(half8v*)&Plds[R * 1024 + p * 8] = dp * dp;
        }
        __syncthreads();
        const u16* vph = vp + 1024 * h;
#pragma unroll
        for (int kt = 0; kt < 32; kt++) {
            const int b = kt * 4 + lg;
            const int p = b ^ ((b >> 3) & 7) ^ (lc & 7);
            half8v af = *(const half8v*)&Plds[lc * 1024 + p * 8];  // A: P[row=lc]
            half8v bf = *(const half8v*)(vph + kt * 32);           // B: V^T[d]
            oacc = mfma_f16(af, bf, oacc);
        }
        if (h == 0) __syncthreads();    // PV(h0) reads done before P(h1) writes
    }
#pragma unroll
    for (int r = 0; r < 4; r++)
        att[(size_t)(q0 + lg * 4 + r) * D + hh * HD + w * 16 + lc] = f2bu(oacc[r]);
}

// ---------------- host side ---------------------------------------------------
extern "C" void kernel_launch(void* const* d_in, const int* in_sizes, int n_in,
                              void* d_out, int out_size, void* d_ws, size_t ws_size,
                              hipStream_t stream)
{
    const float* inp  = (const float*)d_in[0];
    const int*   mask = (const int*)d_in[1];
    const float* wq   = (const float*)d_in[2];
    const float* bq   = (const float*)d_in[3];
    const float* wk   = (const float*)d_in[4];
    const float* bk   = (const float*)d_in[5];
    const float* wv   = (const float*)d_in[6];
    const float* bv   = (const float*)d_in[7];
    const float* wo   = (const float*)d_in[8];
    const float* bo   = (const float*)d_in[9];
    const float* ln1a = (const float*)d_in[10];
    const float* ln1b = (const float*)d_in[11];
    const float* w1   = (const float*)d_in[12];
    const float* b1   = (const float*)d_in[13];
    const float* w2   = (const float*)d_in[14];
    const float* b2   = (const float*)d_in[15];
    const float* ln2a = (const float*)d_in[16];
    const float* ln2b = (const float*)d_in[17];

    const size_t MB = 1u << 20;
    char* w = (char*)d_ws;
    // 32 MB overlay (16-bit bufs unless noted):
    //  [0,8):  wqkvb(6MB) -> w1b (after QKV) -> w2b (after FFN1)
    //  [8,12): x1 -> att -> x2   (bf16)
    //  [12,16): qb_ (f16) -> yb (bf16)
    //  [16,20): kb_ (f16)  \
    //  [20,24): vTb (f16)   > dead after attn -> hb [16,32)
    //  [24,26): wob (bf16) /  (dead after WO, before FFN1 writes hb)
    u16* wqkvb = (u16*)(w + 0 * MB);
    u16* w1b   = (u16*)(w + 0 * MB);
    u16* w2b   = (u16*)(w + 0 * MB);
    u16* x1    = (u16*)(w + 8 * MB);
    u16* att   = x1;
    u16* x2    = x1;
    u16* qb_   = (u16*)(w + 12 * MB);
    u16* yb    = (u16*)(w + 12 * MB);
    u16* kb_   = (u16*)(w + 16 * MB);
    u16* vTb   = (u16*)(w + 20 * MB);
    u16* wob   = (u16*)(w + 24 * MB);
    u16* hb    = (u16*)(w + 16 * MB);
    float* outF = (float*)d_out;

    // 0. weight conversions: QKV concat + WO
    cvt_kernel<<<1024, 256, 0, stream>>>(wq, wqkvb,                   (D * D) / 4);
    cvt_kernel<<<1024, 256, 0, stream>>>(wk, wqkvb + 1024 * 1024,     (D * D) / 4);
    cvt_kernel<<<1024, 256, 0, stream>>>(wv, wqkvb + 2 * 1024 * 1024, (D * D) / 4);
    cvt_kernel<<<1024, 256, 0, stream>>>(wo, wob, (D * D) / 4);
    // 1. LN1 -> bf16
    ln_kernel<float><<<S, 256, 0, stream>>>(inp, ln1a, ln1b, x1);
    // 2. fused QKV projection -> f16 Q [S,D], K [S,D], V^T [D,S]
    gemm_qkv<<<dim3(3 * D / 128, S / 128), 256, 0, stream>>>(
        x1, wqkvb, bq, bk, bv, qb_, kb_, vTb);
    // 3. convert w1 (wqkvb dead)
    cvt_kernel<<<4096, 256, 0, stream>>>(w1, w1b, (DFF * D) / 4);
    // 4. f16 MFMA fused entmax attention -> att bf16 (over x1 slot)
    attn_f16<<<NH * (S / 16), 256, 0, stream>>>(qb_, kb_, vTb, mask, att);
    // 5. WO projection + residual(inp fp32) -> yb bf16  (256 blocks)
    gemm_mfma64<1, 1><<<dim3(D / 64, S / 128), 256, 0, stream>>>(
        att, wob, bo, inp, yb, S, D, D);
    // 6. LN2 -> x2 (att dead)
    ln_kernel<u16><<<S, 256, 0, stream>>>(yb, ln2a, ln2b, x2);
    // 7. FFN1 (+ReLU) -> hb bf16 (kb_/vTb/wob dead)
    gemm_mfma<1, true, 0><<<dim3(DFF / 128, S / 128), 256, 0, stream>>>(
        x2, w1b, b1, nullptr, hb, S, DFF, D);
    // 8. convert w2 (w1b dead)
    cvt_kernel<<<4096, 256, 0, stream>>>(w2, w2b, (DFF * D) / 4);
    // 9. FFN2 + residual(yb bf16) -> fp32 out  (256 blocks)
    gemm_mfma64<0, 2><<<dim3(D / 64, S / 128), 256, 0, stream>>>(
        hb, w2b, b2, yb, outF, S, D, DFF);
}